// Round 4
// baseline (387.648 us; speedup 1.0000x reference)
//
#include <hip/hip_runtime.h>

#define IN_C 512
#define OUT_C 1024
#define NC2 2048
#define NEG_SLOPE 0.2f

typedef short frag8 __attribute__((ext_vector_type(8)));
typedef float f32x4 __attribute__((ext_vector_type(4)));
typedef int i32x4 __attribute__((ext_vector_type(4)));

#define GLOAD_LDS16(g, l) __builtin_amdgcn_global_load_lds(\
    (const __attribute__((address_space(1))) void*)(g), \
    (__attribute__((address_space(3))) void*)(l), 16, 0, 0)

__device__ __forceinline__ unsigned short f2b(float f){
  unsigned u = __float_as_uint(f);
  unsigned r = (u + 0x7fffu + ((u >> 16) & 1u)) >> 16;
  return (unsigned short)r;
}
__device__ __forceinline__ unsigned encf(float f){
  unsigned u = __float_as_uint(f);
  return (u & 0x80000000u) ? ~u : (u | 0x80000000u);
}
__device__ __forceinline__ float decf(unsigned u){
  unsigned v = (u & 0x80000000u) ? (u & 0x7fffffffu) : ~u;
  return __uint_as_float(v);
}
__device__ __forceinline__ float leaky(float v){ return v >= 0.f ? v : NEG_SLOPE * v; }
// bf16x2 + bf16x2 -> bf16x2 (f32 add, round-to-nearest-even)
__device__ __forceinline__ int badd(int a, int b){
  float a0 = __uint_as_float(((unsigned)a) << 16);
  float a1 = __uint_as_float(((unsigned)a) & 0xffff0000u);
  float b0 = __uint_as_float(((unsigned)b) << 16);
  float b1 = __uint_as_float(((unsigned)b) & 0xffff0000u);
  return (int)((unsigned)f2b(a0 + b0) | ((unsigned)f2b(a1 + b1) << 16));
}

// ---------------- fused preprocessing ----------------

__global__ void prep_kernel(const float* __restrict__ W1, const float* __restrict__ W2,
                            const float* __restrict__ Wp1,
                            const float* __restrict__ a_src1, const float* __restrict__ a_dst1,
                            const float* __restrict__ a_src2, const float* __restrict__ a_dst2,
                            unsigned short* __restrict__ WT, unsigned short* __restrict__ Wp1T,
                            float* __restrict__ uv){
  __shared__ float tile[32][33];
  int b = blockIdx.x;
  int tx = threadIdx.x & 31, ty = threadIdx.x >> 5;
  if (b < 1024){
    const float* in = (b >> 9) ? W2 : W1;
    int rowOff = (b >> 9) * OUT_C;
    int bb = b & 511;
    int c0 = (bb & 31) * 32, r0 = (bb >> 5) * 32;
    for (int i = ty; i < 32; i += 8)
      tile[i][tx] = in[(size_t)(r0 + i) * OUT_C + c0 + tx];
    __syncthreads();
    for (int i = ty; i < 32; i += 8)
      WT[(size_t)(c0 + i + rowOff) * IN_C + r0 + tx] = f2b(tile[tx][i]);
  } else if (b < 2048){
    int bb = b - 1024;
    int c0 = (bb & 31) * 32, r0 = (bb >> 5) * 32;
    for (int i = ty; i < 32; i += 8)
      tile[i][tx] = Wp1[(size_t)(r0 + i) * OUT_C + c0 + tx];
    __syncthreads();
    for (int i = ty; i < 32; i += 8)
      Wp1T[(size_t)(c0 + i) * OUT_C + r0 + tx] = f2b(tile[tx][i]);
  } else {
    int g = (b - 2048) * 4 + (threadIdx.x >> 6);
    int lane = threadIdx.x & 63;
    int which = g >> 9;
    int i = g & 511;
    const float* W = (which < 2) ? W1 : W2;
    const float* a = (which == 0) ? a_src1 : (which == 1) ? a_dst1 : (which == 2) ? a_src2 : a_dst2;
    const float* row = W + (size_t)i * OUT_C;
    float s = 0.f;
    for (int j = lane; j < OUT_C; j += 64) s += row[j] * a[j];
    for (int off = 32; off; off >>= 1) s += __shfl_down(s, off);
    if (lane == 0) uv[which * IN_C + i] = s;
  }
}

// ---------------- alpha + selfinit + x->bf16 + zero-init ----------------

__global__ void alpha_kernel(const float* __restrict__ x, const float* __restrict__ uv,
                             unsigned short* __restrict__ xb,
                             float* __restrict__ as1, float* __restrict__ ad1,
                             float* __restrict__ as2, float* __restrict__ ad2,
                             float* __restrict__ self1, float* __restrict__ self2,
                             unsigned* __restrict__ m1e, unsigned* __restrict__ m2e,
                             int* counts, int* cursor, float* colsum, float* wv){
  int n = blockIdx.x;
  int w = threadIdx.x >> 6, lane = threadIdx.x & 63;
  __shared__ float sh[4];
  if (threadIdx.x == 0){ counts[n] = 0; cursor[n] = 0; }
  if (n < 8){
    int i = n * 256 + threadIdx.x;
    if (i < 1024) colsum[i] = 0.f; else wv[i - 1024] = 0.f;
  }
  const float* row = x + (size_t)n * IN_C;
  const float* u = uv + w * IN_C;
  float s = 0.f;
  for (int j = lane; j < IN_C; j += 64){
    float v = row[j];
    s += v * u[j];
    if (w == 0) xb[(size_t)n * IN_C + j] = f2b(v);
  }
  for (int off = 32; off; off >>= 1) s += __shfl_down(s, off);
  if (lane == 0){
    sh[w] = s;
    if (w == 0) as1[n] = s;
    else if (w == 1) ad1[n] = s;
    else if (w == 2) as2[n] = s;
    else ad2[n] = s;
  }
  __syncthreads();
  if (threadIdx.x == 0){
    float e1 = leaky(sh[0] + sh[1]);
    float e2 = leaky(sh[2] + sh[3]);
    self1[n] = e1; self2[n] = e2;
    m1e[n] = encf(e1); m2e[n] = encf(e2);
  }
}

// ---------------- CSR build + edge softmax ----------------

__global__ void histmax_kernel(const int* __restrict__ src, const int* __restrict__ dst,
                               const float* __restrict__ as1, const float* __restrict__ ad1,
                               const float* __restrict__ as2, const float* __restrict__ ad2,
                               int* counts, unsigned* m1e, unsigned* m2e, int E){
  int e = blockIdx.x * 256 + threadIdx.x;
  if (e >= E) return;
  int s = src[e], d = dst[e];
  atomicAdd(&counts[d], 1);
  atomicMax(&m1e[d], encf(leaky(as1[s] + ad1[d])));
  atomicMax(&m2e[d], encf(leaky(as2[s] + ad2[d])));
}

__global__ void scanA_kernel(const int* __restrict__ counts, int* __restrict__ offs,
                             int* __restrict__ bsum, int n){
  __shared__ int wsum[4];
  int i = blockIdx.x * 256 + threadIdx.x;
  int wave = threadIdx.x >> 6, lane = threadIdx.x & 63;
  int v = (i < n) ? counts[i] : 0;
  int sc = v;
  for (int o = 1; o < 64; o <<= 1){
    int t = __shfl_up(sc, o);
    if (lane >= o) sc += t;
  }
  if (lane == 63) wsum[wave] = sc;
  __syncthreads();
  int wp = 0, tot = 0;
#pragma unroll
  for (int k = 0; k < 4; k++){
    int ws = wsum[k];
    if (k < wave) wp += ws;
    tot += ws;
  }
  if (i < n) offs[i] = wp + sc - v;
  if (threadIdx.x == 0) bsum[blockIdx.x] = tot;
}

__global__ void scanB_kernel(int* __restrict__ bsum, int nb){
  int lane = threadIdx.x;
  int v = (lane < nb) ? bsum[lane] : 0;
  int sc = v;
  for (int o = 1; o < 64; o <<= 1){
    int t = __shfl_up(sc, o);
    if (lane >= o) sc += t;
  }
  if (lane < nb) bsum[lane] = sc - v;
}

__global__ void scanC_kernel(int* __restrict__ offs, const int* __restrict__ bsum, int n){
  int i = blockIdx.x * 256 + threadIdx.x;
  if (i < n) offs[i] += bsum[blockIdx.x];
}

__global__ void denominit_kernel(const unsigned* __restrict__ m1e, const unsigned* __restrict__ m2e,
                                 const float* __restrict__ self1, const float* __restrict__ self2,
                                 float* __restrict__ m1, float* __restrict__ m2,
                                 float* __restrict__ den1, float* __restrict__ den2, int N){
  int i = blockIdx.x * 256 + threadIdx.x;
  if (i >= N) return;
  float a = decf(m1e[i]), b = decf(m2e[i]);
  m1[i] = a; m2[i] = b;
  den1[i] = expf(self1[i] - a);
  den2[i] = expf(self2[i] - b);
}

__global__ void scatterexp_kernel(const int* __restrict__ src, const int* __restrict__ dst,
                                  const int* __restrict__ offs, int* cursor,
                                  const float* __restrict__ as1, const float* __restrict__ ad1,
                                  const float* __restrict__ as2, const float* __restrict__ ad2,
                                  const float* __restrict__ m1, const float* __restrict__ m2,
                                  int* __restrict__ nsrc, float* __restrict__ nw1, float* __restrict__ nw2,
                                  float* den1, float* den2, int E){
  int e = blockIdx.x * 256 + threadIdx.x;
  if (e >= E) return;
  int s = src[e], d = dst[e];
  int p = atomicAdd(&cursor[d], 1);
  int idx = offs[d] + p;
  float x1 = expf(leaky(as1[s] + ad1[d]) - m1[d]);
  float x2 = expf(leaky(as2[s] + ad2[d]) - m2[d]);
  nsrc[idx] = s; nw1[idx] = x1; nw2[idx] = x2;
  atomicAdd(&den1[d], x1);
  atomicAdd(&den2[d], x2);
}

// ---------------- aggregate-first ----------------

#define AGG_FMA8(ACC, W, U) \
  ACC[0] += (W) * __uint_as_float(((unsigned)(U).x) << 16); \
  ACC[1] += (W) * __uint_as_float(((unsigned)(U).x) & 0xffff0000u); \
  ACC[2] += (W) * __uint_as_float(((unsigned)(U).y) << 16); \
  ACC[3] += (W) * __uint_as_float(((unsigned)(U).y) & 0xffff0000u); \
  ACC[4] += (W) * __uint_as_float(((unsigned)(U).z) << 16); \
  ACC[5] += (W) * __uint_as_float(((unsigned)(U).z) & 0xffff0000u); \
  ACC[6] += (W) * __uint_as_float(((unsigned)(U).w) << 16); \
  ACC[7] += (W) * __uint_as_float(((unsigned)(U).w) & 0xffff0000u);

__global__ __launch_bounds__(256) void aggx_kernel(
    const int* __restrict__ counts, const int* __restrict__ offs,
    const int* __restrict__ nsrc, const float* __restrict__ nw1, const float* __restrict__ nw2,
    const float* __restrict__ den1, const float* __restrict__ den2,
    const float* __restrict__ self1, const float* __restrict__ self2,
    const float* __restrict__ m1, const float* __restrict__ m2,
    const unsigned short* __restrict__ xb,
    unsigned short* __restrict__ xa1b, unsigned short* __restrict__ xa2b, int N){
  int tid = threadIdx.x;
  int g = tid >> 4, hl = tid & 15;
  int grpbase = tid & 48;
  int d = blockIdx.y * 16 + g;
  if (d >= N) return;
  int colbase = blockIdx.x * 128 + hl * 8;
  float inv1 = 1.f / den1[d], inv2 = 1.f / den2[d];
  int deg = counts[d], off = offs[d];
  float acc1[8] = {0,0,0,0,0,0,0,0}, acc2[8] = {0,0,0,0,0,0,0,0};
  const unsigned short* Xb = xb + colbase;
  for (int base = 0; base < deg; base += 16){
    int i = base + hl;
    int s = 0; float w1 = 0.f, w2 = 0.f;
    if (i < deg){
      int p = off + i;
      s = nsrc[p];
      w1 = nw1[p] * inv1;
      w2 = nw2[p] * inv2;
    }
    int cnt = min(16, deg - base);
#pragma unroll 4
    for (int j = 0; j < cnt; j++){
      int sj = __shfl(s, grpbase + j);
      float w1j = __shfl(w1, grpbase + j);
      float w2j = __shfl(w2, grpbase + j);
      int4 u = *(const int4*)(Xb + (size_t)sj * IN_C);
      AGG_FMA8(acc1, w1j, u)
      AGG_FMA8(acc2, w2j, u)
    }
  }
  {
    float ws1 = expf(self1[d] - m1[d]) * inv1;
    float ws2 = expf(self2[d] - m2[d]) * inv2;
    int4 u = *(const int4*)(Xb + (size_t)d * IN_C);
    AGG_FMA8(acc1, ws1, u)
    AGG_FMA8(acc2, ws2, u)
  }
  size_t outb = (size_t)d * IN_C + colbase;
  i32x4 o1, o2;
  o1.x = (int)((unsigned)f2b(acc1[0]) | ((unsigned)f2b(acc1[1]) << 16));
  o1.y = (int)((unsigned)f2b(acc1[2]) | ((unsigned)f2b(acc1[3]) << 16));
  o1.z = (int)((unsigned)f2b(acc1[4]) | ((unsigned)f2b(acc1[5]) << 16));
  o1.w = (int)((unsigned)f2b(acc1[6]) | ((unsigned)f2b(acc1[7]) << 16));
  o2.x = (int)((unsigned)f2b(acc2[0]) | ((unsigned)f2b(acc2[1]) << 16));
  o2.y = (int)((unsigned)f2b(acc2[2]) | ((unsigned)f2b(acc2[3]) << 16));
  o2.z = (int)((unsigned)f2b(acc2[4]) | ((unsigned)f2b(acc2[5]) << 16));
  o2.w = (int)((unsigned)f2b(acc2[6]) | ((unsigned)f2b(acc2[7]) << 16));
  __builtin_nontemporal_store(o1, (i32x4*)(xa1b + outb));
  __builtin_nontemporal_store(o2, (i32x4*)(xa2b + outb));
}

// ---------------- shared MFMA fragment compute (256x256 tile, 8 waves 2x4) ---------

#define COMP256(AB, BB) do{ \
    frag8 af[8], bf[4]; \
    _Pragma("unroll") \
    for (int mi = 0; mi < 8; mi++) af[mi] = *(const frag8*)&(AB)[(wr*128 + mi*16 + l16) * 32 + qs]; \
    _Pragma("unroll") \
    for (int nj = 0; nj < 4; nj++) bf[nj] = *(const frag8*)&(BB)[(wc*64 + nj*16 + l16) * 32 + qs]; \
    _Pragma("unroll") \
    for (int mi = 0; mi < 8; mi++) \
      _Pragma("unroll") \
      for (int nj = 0; nj < 4; nj++) \
        acc[mi][nj] = __builtin_amdgcn_mfma_f32_16x16x32_bf16(af[mi], bf[nj], acc[mi][nj], 0, 0, 0); \
  }while(0)

// ---------------- GEMM-H: one 256x256 tile per block, g in {0,1} selects gemm.
// 3-buffer distance-2 prefetch, counted vmcnt(4) + raw s_barrier (never drains
// in-flight prefetch). Writes h1/h2 with bias+PReLU applied.

__global__ __launch_bounds__(512, 2) void gemmh_kernel(const unsigned short* __restrict__ A1,
                                                       const unsigned short* __restrict__ A2,
                                                       const unsigned short* __restrict__ BT,
                                                       const float* __restrict__ b1,
                                                       const float* __restrict__ b2,
                                                       const float* __restrict__ prelu_a,
                                                       unsigned short* __restrict__ h1,
                                                       unsigned short* __restrict__ h2,
                                                       int M, int Mtiles){
  // bijective XCD remap: nwg = Mtiles*8 (divisible by 8)
  const int per = Mtiles;                       // nwg/8
  const int sw = (blockIdx.x & 7) * per + (blockIdx.x >> 3);
  const int bm = (sw >> 3) * 256;
  const int g  = (sw >> 2) & 1;
  const int bn = (sw & 3) * 256;
  __shared__ unsigned short Al[3][256 * 32];    // 48 KB
  __shared__ unsigned short Bl[3][256 * 32];    // 48 KB
  const int t = threadIdx.x;
  const int lane = t & 63, wid = t >> 6;
  const int wr = wid >> 2, wc = wid & 3;        // 2x4 wave grid, wave tile 128x64
  const int l16 = lane & 15, q = lane >> 4;
  const int qs = (q ^ ((l16 >> 1) & 3)) * 8;                // swizzled read slot
  const int lch = (((lane & 3) ^ ((lane >> 3) & 3)) * 8);   // pre-swizzled source chunk
  f32x4 acc[8][4] = {};
  const unsigned short* Asrc = g ? A2 : A1;
  const int r0 = wid * 16 + (lane >> 2);
  const unsigned short* pa0 = Asrc + (size_t)min(bm + r0,       M - 1) * IN_C + lch;
  const unsigned short* pa1 = Asrc + (size_t)min(bm + r0 + 128, M - 1) * IN_C + lch;
  const unsigned short* pb0 = BT + (size_t)(g * OUT_C + bn + r0      ) * IN_C + lch;
  const unsigned short* pb1 = BT + (size_t)(g * OUT_C + bn + r0 + 128) * IN_C + lch;
  const int so0 = (wid * 16) * 32;
  const int so1 = (wid * 16 + 128) * 32;

#define STGH(B, k0) do{ \
    GLOAD_LDS16(pa0 + (k0), &Al[B][so0]); \
    GLOAD_LDS16(pa1 + (k0), &Al[B][so1]); \
    GLOAD_LDS16(pb0 + (k0), &Bl[B][so0]); \
    GLOAD_LDS16(pb1 + (k0), &Bl[B][so1]); \
  }while(0)

  STGH(0, 0);
  STGH(1, 32);
  int cur = 0;
#pragma unroll 1
  for (int it = 0; it < 16; ++it){
    asm volatile("s_waitcnt vmcnt(4)" ::: "memory");   // chunk `it` landed (keep it+1's 4)
    __builtin_amdgcn_s_barrier();                      // cross-wave: landed for all; prev reads done
    int nb = cur ? cur - 1 : 2;                        // (cur+2)%3
    int kc = it + 2 > 15 ? 15 : it + 2;                // clamp: tail stages are never read
    STGH(nb, kc * 32);
    COMP256(Al[cur], Bl[cur]);
    cur = cur < 2 ? cur + 1 : 0;
  }
#undef STGH

  const float* bias = g ? b2 : b1;
  unsigned short* H = g ? h2 : h1;
  float pa = prelu_a[0];
#pragma unroll
  for (int mi = 0; mi < 8; mi++){
#pragma unroll
    for (int r = 0; r < 4; r++){
      int row = bm + wr*128 + mi*16 + q*4 + r;
      if (row >= M) continue;
#pragma unroll
      for (int nj = 0; nj < 4; nj++){
        int col = bn + wc*64 + nj*16 + l16;
        float v = acc[mi][nj][r] + bias[col];
        v = v >= 0.f ? v : pa * v;
        __builtin_nontemporal_store(f2b(v), &H[(size_t)row * OUT_C + col]);
      }
    }
  }
}

// ---------------- GEMM2: 256x256 tile; colsum += sum_rows tanh((h1+h2) @ Wp1 + bp1).
// B via gload_lds (3-buf dist-2); A = h1+h2 reg-staged (T14 split: load 2 ahead,
// ds_write 1 behind). Counted vmcnt(2) + lgkmcnt(0) + raw barrier per chunk.

__global__ __launch_bounds__(512, 2) void gemm2_kernel(const unsigned short* __restrict__ h1,
                                                       const unsigned short* __restrict__ h2,
                                                       const unsigned short* __restrict__ BT,
                                                       const float* __restrict__ bp1,
                                                       float* __restrict__ colsum,
                                                       int M, int Mtiles){
  const int nwg = Mtiles * 4;
  const int bid = blockIdx.x;
  const int sw = (nwg & 7) ? bid : ((bid & 7) * (nwg >> 3) + (bid >> 3));
  const int bm = (sw >> 2) * 256;
  const int bn = (sw & 3) * 256;
  __shared__ unsigned short Al[3][256 * 32];
  __shared__ unsigned short Bl[3][256 * 32];
  __shared__ float cs[256];
  const int t = threadIdx.x;
  const int lane = t & 63, wid = t >> 6;
  const int wr = wid >> 2, wc = wid & 3;
  const int l16 = lane & 15, q = lane >> 4;
  const int qs = (q ^ ((l16 >> 1) & 3)) * 8;
  const int lch = (((lane & 3) ^ ((lane >> 3) & 3)) * 8);
  if (t < 256) cs[t] = 0.f;
  f32x4 acc[8][4] = {};
  // B staging (gload_lds)
  const int r0 = wid * 16 + (lane >> 2);
  const unsigned short* pb0 = BT + (size_t)(bn + r0      ) * OUT_C + lch;
  const unsigned short* pb1 = BT + (size_t)(bn + r0 + 128) * OUT_C + lch;
  const int so0 = (wid * 16) * 32;
  const int so1 = (wid * 16 + 128) * 32;
  // A reg-staging: thread -> row ra, 16-col half hc
  const int ra = t >> 1, hc = t & 1;
  const size_t arowoff = (size_t)min(bm + ra, M - 1) * OUT_C + hc * 16;
  const unsigned short* ph1 = h1 + arowoff;
  const unsigned short* ph2 = h2 + arowoff;
  const int rs = (ra >> 1) & 3;
  const int wa0 = ra * 32 + ((hc * 2) ^ rs) * 8;
  const int wa1 = ra * 32 + ((hc * 2 + 1) ^ rs) * 8;
  int4 pA_h1a, pA_h1b, pA_h2a, pA_h2b;
  int4 pB_h1a, pB_h1b, pB_h2a, pB_h2b;

#define LOADA(D1A, D1B, D2A, D2B, KC) do{ \
    D1A = *(const int4*)(ph1 + (KC) * 32); \
    D1B = *(const int4*)(ph1 + (KC) * 32 + 8); \
    D2A = *(const int4*)(ph2 + (KC) * 32); \
    D2B = *(const int4*)(ph2 + (KC) * 32 + 8); \
  }while(0)
#define WRITEA(NW, C1A, C1B, C2A, C2B) do{ \
    int4 w0, w1; \
    w0.x = badd((C1A).x, (C2A).x); w0.y = badd((C1A).y, (C2A).y); \
    w0.z = badd((C1A).z, (C2A).z); w0.w = badd((C1A).w, (C2A).w); \
    w1.x = badd((C1B).x, (C2B).x); w1.y = badd((C1B).y, (C2B).y); \
    w1.z = badd((C1B).z, (C2B).z); w1.w = badd((C1B).w, (C2B).w); \
    *(int4*)&Al[NW][wa0] = w0; \
    *(int4*)&Al[NW][wa1] = w1; \
  }while(0)
#define G2BODY(T, C1A, C1B, C2A, C2B, N1A, N1B, N2A, N2B) do{ \
    asm volatile("s_waitcnt vmcnt(2)" ::: "memory"); \
    asm volatile("s_waitcnt lgkmcnt(0)" ::: "memory"); \
    __builtin_amdgcn_s_barrier(); \
    int kc = (T) + 2 > 31 ? 31 : (T) + 2; \
    LOADA(N1A, N1B, N2A, N2B, kc); \
    GLOAD_LDS16(pb0 + kc * 32, &Bl[nb][so0]); \
    GLOAD_LDS16(pb1 + kc * 32, &Bl[nb][so1]); \
    WRITEA(nw, C1A, C1B, C2A, C2B); \
    COMP256(Al[cur], Bl[cur]); \
    cur = cur < 2 ? cur + 1 : 0; \
    nb  = nb  < 2 ? nb  + 1 : 0; \
    nw  = nw  < 2 ? nw  + 1 : 0; \
  }while(0)

  // prologue: chunk0 -> setA + Bbuf0; chunk1 -> setB + Bbuf1; write A(0)
  LOADA(pA_h1a, pA_h1b, pA_h2a, pA_h2b, 0);
  GLOAD_LDS16(pb0, &Bl[0][so0]);
  GLOAD_LDS16(pb1, &Bl[0][so1]);
  LOADA(pB_h1a, pB_h1b, pB_h2a, pB_h2b, 1);
  GLOAD_LDS16(pb0 + 32, &Bl[1][so0]);
  GLOAD_LDS16(pb1 + 32, &Bl[1][so1]);
  WRITEA(0, pA_h1a, pA_h1b, pA_h2a, pA_h2b);   // compiler waits the A(0) regs
  int cur = 0, nb = 2, nw = 1;
#pragma unroll 1
  for (int it = 0; it < 32; it += 2){
    G2BODY(it,     pB_h1a, pB_h1b, pB_h2a, pB_h2b, pA_h1a, pA_h1b, pA_h2a, pA_h2b);
    G2BODY(it + 1, pA_h1a, pA_h1b, pA_h2a, pA_h2b, pB_h1a, pB_h1b, pB_h2a, pB_h2b);
  }
#undef G2BODY
#undef WRITEA
#undef LOADA

#pragma unroll
  for (int nj = 0; nj < 4; nj++){
    int col = bn + wc*64 + nj*16 + l16;
    float bias = bp1[col];
    float p = 0.f;
#pragma unroll
    for (int mi = 0; mi < 8; mi++){
#pragma unroll
      for (int r = 0; r < 4; r++){
        int row = bm + wr*128 + mi*16 + q*4 + r;
        float tv = tanhf(acc[mi][nj][r] + bias);
        if (row < M) p += tv;
      }
    }
    p += __shfl_xor(p, 16);
    p += __shfl_xor(p, 32);
    if (q == 0) atomicAdd(&cs[wc*64 + nj*16 + l16], p);
  }
  __syncthreads();
  if (t < 256) atomicAdd(&colsum[bn + t], cs[t]);
}

// ---------------- semantic attention tail ----------------

__global__ void wproj_kernel(const float* __restrict__ colsum, const float* __restrict__ Wp2,
                             float* __restrict__ wv){
  int o = blockIdx.x * 256 + threadIdx.x;
  int c0 = blockIdx.y * 128;
  float acc = 0.f;
  for (int c = c0; c < c0 + 128; c++) acc += colsum[c] * Wp2[(size_t)c * OUT_C + o];
  atomicAdd(&wv[o], acc);
}

__global__ __launch_bounds__(1024) void softmax_kernel(const float* __restrict__ wv,
                                                       float* __restrict__ att, float invN){
  int o = threadIdx.x;
  __shared__ float red[1024];
  float w = wv[o] * invN;
  red[o] = w; __syncthreads();
  for (int s = 512; s > 0; s >>= 1){ if (o < s) red[o] = fmaxf(red[o], red[o + s]); __syncthreads(); }
  float m = red[0]; __syncthreads();
  float e = expf(w - m);
  red[o] = e; __syncthreads();
  for (int s = 512; s > 0; s >>= 1){ if (o < s) red[o] += red[o + s]; __syncthreads(); }
  att[o] = e / red[0];
}

// out = att*h1 + (1-att)*h2 = h2 + att*(h1-h2)
__global__ void combine_kernel(const float* __restrict__ att, const unsigned short* __restrict__ h1,
                               const unsigned short* __restrict__ h2, float* __restrict__ out, int total8){
  int i = blockIdx.x * 256 + threadIdx.x;
  if (i >= total8) return;
  int colb = (i & 127) * 8;
  int4 u1 = ((const int4*)h1)[i];
  int4 u2 = ((const int4*)h2)[i];
  float4 a0 = *(const float4*)(att + colb);
  float4 a1 = *(const float4*)(att + colb + 4);
  float o[8]; float v1, v2;
  v1 = __uint_as_float(((unsigned)u1.x) << 16);         v2 = __uint_as_float(((unsigned)u2.x) << 16);
  o[0] = v2 + a0.x * (v1 - v2);
  v1 = __uint_as_float(((unsigned)u1.x) & 0xffff0000u); v2 = __uint_as_float(((unsigned)u2.x) & 0xffff0000u);
  o[1] = v2 + a0.y * (v1 - v2);
  v1 = __uint_as_float(((unsigned)u1.y) << 16);         v2 = __uint_as_float(((unsigned)u2.y) << 16);
  o[2] = v2 + a0.z * (v1 - v2);
  v1 = __uint_as_float(((unsigned)u1.y) & 0xffff0000u); v2 = __uint_as_float(((unsigned)u2.y) & 0xffff0000u);
  o[3] = v2 + a0.w * (v1 - v2);
  v1 = __uint_as_float(((unsigned)u1.z) << 16);         v2 = __uint_as_float(((unsigned)u2.z) << 16);
  o[4] = v2 + a1.x * (v1 - v2);
  v1 = __uint_as_float(((unsigned)u1.z) & 0xffff0000u); v2 = __uint_as_float(((unsigned)u2.z) & 0xffff0000u);
  o[5] = v2 + a1.y * (v1 - v2);
  v1 = __uint_as_float(((unsigned)u1.w) << 16);         v2 = __uint_as_float(((unsigned)u2.w) << 16);
  o[6] = v2 + a1.z * (v1 - v2);
  v1 = __uint_as_float(((unsigned)u1.w) & 0xffff0000u); v2 = __uint_as_float(((unsigned)u2.w) & 0xffff0000u);
  o[7] = v2 + a1.w * (v1 - v2);
  f32x4 f0; f0[0] = o[0]; f0[1] = o[1]; f0[2] = o[2]; f0[3] = o[3];
  f32x4 f1; f1[0] = o[4]; f1[1] = o[5]; f1[2] = o[6]; f1[3] = o[7];
  __builtin_nontemporal_store(f0, (f32x4*)(out + (size_t)i * 8));
  __builtin_nontemporal_store(f1, (f32x4*)(out + (size_t)i * 8 + 4));
}

// ---------------- launch ----------------

extern "C" void kernel_launch(void* const* d_in, const int* in_sizes, int n_in,
                              void* d_out, int out_size, void* d_ws, size_t ws_size,
                              hipStream_t stream){
  const float* x      = (const float*)d_in[0];
  const int*   edge   = (const int*)d_in[1];
  const float* W1     = (const float*)d_in[2];
  const float* a_src1 = (const float*)d_in[3];
  const float* a_dst1 = (const float*)d_in[4];
  const float* b1     = (const float*)d_in[5];
  const float* W2     = (const float*)d_in[6];
  const float* a_src2 = (const float*)d_in[7];
  const float* a_dst2 = (const float*)d_in[8];
  const float* b2     = (const float*)d_in[9];
  const float* prelu_a= (const float*)d_in[10];
  const float* Wp1    = (const float*)d_in[11];
  const float* bp1    = (const float*)d_in[12];
  const float* Wp2    = (const float*)d_in[13];
  const int N = in_sizes[0] / IN_C;
  const int E = in_sizes[1] / 2;
  const int* srcArr = edge;
  const int* dstArr = edge + E;

  char* ws = (char*)d_ws;
  size_t o = 0;
  auto alloc = [&](size_t b) -> char* {
    char* p = ws + o;
    o = (o + b + 255) & ~(size_t)255;
    return p;
  };
  unsigned short* xb    = (unsigned short*)alloc((size_t)N * IN_C * 2);
  unsigned short* WT    = (unsigned short*)alloc((size_t)NC2 * IN_C * 2);
  unsigned short* Wp1T  = (unsigned short*)alloc((size_t)OUT_C * OUT_C * 2);
  unsigned short* xa1b  = (unsigned short*)alloc((size_t)N * IN_C * 2);
  unsigned short* xa2b  = (unsigned short*)alloc((size_t)N * IN_C * 2);
  unsigned short* h1    = (unsigned short*)alloc((size_t)N * OUT_C * 2);
  unsigned short* h2    = (unsigned short*)alloc((size_t)N * OUT_C * 2);
  float*          uv    = (float*)alloc(4 * IN_C * 4);
  float*          as1   = (float*)alloc((size_t)4 * N * 4);
  float* ad1 = as1 + N; float* as2 = as1 + 2 * N; float* ad2 = as1 + 3 * N;
  float*          self1 = (float*)alloc((size_t)2 * N * 4); float* self2 = self1 + N;
  unsigned*       m1e   = (unsigned*)alloc((size_t)2 * N * 4); unsigned* m2e = m1e + N;
  float*          m1    = (float*)alloc((size_t)2 * N * 4); float* m2 = m1 + N;
  float*          den1  = (float*)alloc((size_t)2 * N * 4); float* den2 = den1 + N;
  int*            counts= (int*)alloc((size_t)N * 4);
  int*            offs  = (int*)alloc((size_t)(N + 1) * 4);
  int*            cursor= (int*)alloc((size_t)N * 4);
  int*            bsum  = (int*)alloc(64 * 4);
  int*            nsrc  = (int*)alloc((size_t)E * 4);
  float*          nw1   = (float*)alloc((size_t)E * 4);
  float*          nw2   = (float*)alloc((size_t)E * 4);
  float*          colsum= (float*)alloc(OUT_C * 4);
  float*          wv    = (float*)alloc(OUT_C * 4);
  float*          att   = (float*)alloc(OUT_C * 4);

  const int Mt = (N + 255) / 256;
  const int nchunk = (N + 255) / 256;

  prep_kernel<<<2560, 256, 0, stream>>>(W1, W2, Wp1, a_src1, a_dst1, a_src2, a_dst2, WT, Wp1T, uv);
  alpha_kernel<<<N, 256, 0, stream>>>(x, uv, xb, as1, ad1, as2, ad2, self1, self2, m1e, m2e,
                                      counts, cursor, colsum, wv);
  histmax_kernel<<<(E + 255) / 256, 256, 0, stream>>>(srcArr, dstArr, as1, ad1, as2, ad2,
                                                      counts, m1e, m2e, E);
  scanA_kernel<<<nchunk, 256, 0, stream>>>(counts, offs, bsum, N);
  scanB_kernel<<<1, 64, 0, stream>>>(bsum, nchunk);
  scanC_kernel<<<nchunk, 256, 0, stream>>>(offs, bsum, N);
  denominit_kernel<<<nchunk, 256, 0, stream>>>(m1e, m2e, self1, self2, m1, m2, den1, den2, N);
  scatterexp_kernel<<<(E + 255) / 256, 256, 0, stream>>>(srcArr, dstArr, offs, cursor,
                                                         as1, ad1, as2, ad2, m1, m2,
                                                         nsrc, nw1, nw2, den1, den2, E);
  aggx_kernel<<<dim3(4, (N + 15) / 16), 256, 0, stream>>>(counts, offs, nsrc, nw1, nw2, den1, den2,
                                                          self1, self2, m1, m2, xb, xa1b, xa2b, N);
  gemmh_kernel<<<Mt * 8, 512, 0, stream>>>(xa1b, xa2b, WT, b1, b2, prelu_a, h1, h2, N, Mt);
  gemm2_kernel<<<Mt * 4, 512, 0, stream>>>(h1, h2, Wp1T, bp1, colsum, N, Mt);
  wproj_kernel<<<dim3(4, 8), 256, 0, stream>>>(colsum, Wp2, wv);
  softmax_kernel<<<1, 1024, 0, stream>>>(wv, att, 1.0f / (float)N);
  combine_kernel<<<(N * OUT_C / 8 + 255) / 256, 256, 0, stream>>>(att, h1, h2, (float*)d_out,
                                                                  N * OUT_C / 8);
}

// Round 5
// 333.667 us; speedup vs baseline: 1.1618x; 1.1618x over previous
//
#include <hip/hip_runtime.h>

#define IN_C 512
#define OUT_C 1024
#define NC2 2048
#define NEG_SLOPE 0.2f

typedef short frag8 __attribute__((ext_vector_type(8)));
typedef float f32x4 __attribute__((ext_vector_type(4)));
typedef int i32x4 __attribute__((ext_vector_type(4)));

#define GLOAD_LDS16(g, l) __builtin_amdgcn_global_load_lds(\
    (const __attribute__((address_space(1))) void*)(g), \
    (__attribute__((address_space(3))) void*)(l), 16, 0, 0)

__device__ __forceinline__ unsigned short f2b(float f){
  unsigned u = __float_as_uint(f);
  unsigned r = (u + 0x7fffu + ((u >> 16) & 1u)) >> 16;
  return (unsigned short)r;
}
__device__ __forceinline__ unsigned encf(float f){
  unsigned u = __float_as_uint(f);
  return (u & 0x80000000u) ? ~u : (u | 0x80000000u);
}
__device__ __forceinline__ float decf(unsigned u){
  unsigned v = (u & 0x80000000u) ? (u & 0x7fffffffu) : ~u;
  return __uint_as_float(v);
}
__device__ __forceinline__ float leaky(float v){ return v >= 0.f ? v : NEG_SLOPE * v; }

// ---------------- fused preprocessing ----------------

__global__ void prep_kernel(const float* __restrict__ W1, const float* __restrict__ W2,
                            const float* __restrict__ Wp1,
                            const float* __restrict__ a_src1, const float* __restrict__ a_dst1,
                            const float* __restrict__ a_src2, const float* __restrict__ a_dst2,
                            unsigned short* __restrict__ WT, unsigned short* __restrict__ Wp1T,
                            float* __restrict__ uv){
  __shared__ float tile[32][33];
  int b = blockIdx.x;
  int tx = threadIdx.x & 31, ty = threadIdx.x >> 5;
  if (b < 1024){
    const float* in = (b >> 9) ? W2 : W1;
    int rowOff = (b >> 9) * OUT_C;
    int bb = b & 511;
    int c0 = (bb & 31) * 32, r0 = (bb >> 5) * 32;
    for (int i = ty; i < 32; i += 8)
      tile[i][tx] = in[(size_t)(r0 + i) * OUT_C + c0 + tx];
    __syncthreads();
    for (int i = ty; i < 32; i += 8)
      WT[(size_t)(c0 + i + rowOff) * IN_C + r0 + tx] = f2b(tile[tx][i]);
  } else if (b < 2048){
    int bb = b - 1024;
    int c0 = (bb & 31) * 32, r0 = (bb >> 5) * 32;
    for (int i = ty; i < 32; i += 8)
      tile[i][tx] = Wp1[(size_t)(r0 + i) * OUT_C + c0 + tx];
    __syncthreads();
    for (int i = ty; i < 32; i += 8)
      Wp1T[(size_t)(c0 + i) * OUT_C + r0 + tx] = f2b(tile[tx][i]);
  } else {
    int g = (b - 2048) * 4 + (threadIdx.x >> 6);
    int lane = threadIdx.x & 63;
    int which = g >> 9;
    int i = g & 511;
    const float* W = (which < 2) ? W1 : W2;
    const float* a = (which == 0) ? a_src1 : (which == 1) ? a_dst1 : (which == 2) ? a_src2 : a_dst2;
    const float* row = W + (size_t)i * OUT_C;
    float s = 0.f;
    for (int j = lane; j < OUT_C; j += 64) s += row[j] * a[j];
    for (int off = 32; off; off >>= 1) s += __shfl_down(s, off);
    if (lane == 0) uv[which * IN_C + i] = s;
  }
}

// ---------------- alpha + selfinit + x->bf16 + zero-init ----------------

__global__ void alpha_kernel(const float* __restrict__ x, const float* __restrict__ uv,
                             unsigned short* __restrict__ xb,
                             float* __restrict__ as1, float* __restrict__ ad1,
                             float* __restrict__ as2, float* __restrict__ ad2,
                             float* __restrict__ self1, float* __restrict__ self2,
                             unsigned* __restrict__ m1e, unsigned* __restrict__ m2e,
                             int* counts, int* cursor, float* colsum, float* wv){
  int n = blockIdx.x;
  int w = threadIdx.x >> 6, lane = threadIdx.x & 63;
  __shared__ float sh[4];
  if (threadIdx.x == 0){ counts[n] = 0; cursor[n] = 0; }
  if (n < 8){
    int i = n * 256 + threadIdx.x;
    if (i < 1024) colsum[i] = 0.f; else wv[i - 1024] = 0.f;
  }
  const float* row = x + (size_t)n * IN_C;
  const float* u = uv + w * IN_C;
  float s = 0.f;
  for (int j = lane; j < IN_C; j += 64){
    float v = row[j];
    s += v * u[j];
    if (w == 0) xb[(size_t)n * IN_C + j] = f2b(v);
  }
  for (int off = 32; off; off >>= 1) s += __shfl_down(s, off);
  if (lane == 0){
    sh[w] = s;
    if (w == 0) as1[n] = s;
    else if (w == 1) ad1[n] = s;
    else if (w == 2) as2[n] = s;
    else ad2[n] = s;
  }
  __syncthreads();
  if (threadIdx.x == 0){
    float e1 = leaky(sh[0] + sh[1]);
    float e2 = leaky(sh[2] + sh[3]);
    self1[n] = e1; self2[n] = e2;
    m1e[n] = encf(e1); m2e[n] = encf(e2);
  }
}

// ---------------- CSR build + edge softmax ----------------

__global__ void histmax_kernel(const int* __restrict__ src, const int* __restrict__ dst,
                               const float* __restrict__ as1, const float* __restrict__ ad1,
                               const float* __restrict__ as2, const float* __restrict__ ad2,
                               int* counts, unsigned* m1e, unsigned* m2e, int E){
  int e = blockIdx.x * 256 + threadIdx.x;
  if (e >= E) return;
  int s = src[e], d = dst[e];
  atomicAdd(&counts[d], 1);
  atomicMax(&m1e[d], encf(leaky(as1[s] + ad1[d])));
  atomicMax(&m2e[d], encf(leaky(as2[s] + ad2[d])));
}

__global__ void scanA_kernel(const int* __restrict__ counts, int* __restrict__ offs,
                             int* __restrict__ bsum, int n){
  __shared__ int wsum[4];
  int i = blockIdx.x * 256 + threadIdx.x;
  int wave = threadIdx.x >> 6, lane = threadIdx.x & 63;
  int v = (i < n) ? counts[i] : 0;
  int sc = v;
  for (int o = 1; o < 64; o <<= 1){
    int t = __shfl_up(sc, o);
    if (lane >= o) sc += t;
  }
  if (lane == 63) wsum[wave] = sc;
  __syncthreads();
  int wp = 0, tot = 0;
#pragma unroll
  for (int k = 0; k < 4; k++){
    int ws = wsum[k];
    if (k < wave) wp += ws;
    tot += ws;
  }
  if (i < n) offs[i] = wp + sc - v;
  if (threadIdx.x == 0) bsum[blockIdx.x] = tot;
}

__global__ void scanB_kernel(int* __restrict__ bsum, int nb){
  int lane = threadIdx.x;
  int v = (lane < nb) ? bsum[lane] : 0;
  int sc = v;
  for (int o = 1; o < 64; o <<= 1){
    int t = __shfl_up(sc, o);
    if (lane >= o) sc += t;
  }
  if (lane < nb) bsum[lane] = sc - v;
}

// scanC + denominit fused (one fewer launch; bodies independent)
__global__ void scanC_kernel(int* __restrict__ offs, const int* __restrict__ bsum,
                             const unsigned* __restrict__ m1e, const unsigned* __restrict__ m2e,
                             const float* __restrict__ self1, const float* __restrict__ self2,
                             float* __restrict__ m1, float* __restrict__ m2,
                             float* __restrict__ den1, float* __restrict__ den2, int n){
  int i = blockIdx.x * 256 + threadIdx.x;
  if (i >= n) return;
  offs[i] += bsum[blockIdx.x];
  float a = decf(m1e[i]), b = decf(m2e[i]);
  m1[i] = a; m2[i] = b;
  den1[i] = expf(self1[i] - a);
  den2[i] = expf(self2[i] - b);
}

__global__ void scatterexp_kernel(const int* __restrict__ src, const int* __restrict__ dst,
                                  const int* __restrict__ offs, int* cursor,
                                  const float* __restrict__ as1, const float* __restrict__ ad1,
                                  const float* __restrict__ as2, const float* __restrict__ ad2,
                                  const float* __restrict__ m1, const float* __restrict__ m2,
                                  int* __restrict__ nsrc, float* __restrict__ nw1, float* __restrict__ nw2,
                                  float* den1, float* den2, int E){
  int e = blockIdx.x * 256 + threadIdx.x;
  if (e >= E) return;
  int s = src[e], d = dst[e];
  int p = atomicAdd(&cursor[d], 1);
  int idx = offs[d] + p;
  float x1 = expf(leaky(as1[s] + ad1[d]) - m1[d]);
  float x2 = expf(leaky(as2[s] + ad2[d]) - m2[d]);
  nsrc[idx] = s; nw1[idx] = x1; nw2[idx] = x2;
  atomicAdd(&den1[d], x1);
  atomicAdd(&den2[d], x2);
}

// ---------------- aggregate-first ----------------

#define AGG_FMA8(ACC, W, U) \
  ACC[0] += (W) * __uint_as_float(((unsigned)(U).x) << 16); \
  ACC[1] += (W) * __uint_as_float(((unsigned)(U).x) & 0xffff0000u); \
  ACC[2] += (W) * __uint_as_float(((unsigned)(U).y) << 16); \
  ACC[3] += (W) * __uint_as_float(((unsigned)(U).y) & 0xffff0000u); \
  ACC[4] += (W) * __uint_as_float(((unsigned)(U).z) << 16); \
  ACC[5] += (W) * __uint_as_float(((unsigned)(U).z) & 0xffff0000u); \
  ACC[6] += (W) * __uint_as_float(((unsigned)(U).w) << 16); \
  ACC[7] += (W) * __uint_as_float(((unsigned)(U).w) & 0xffff0000u);

__global__ __launch_bounds__(256, 4) void aggx_kernel(
    const int* __restrict__ counts, const int* __restrict__ offs,
    const int* __restrict__ nsrc, const float* __restrict__ nw1, const float* __restrict__ nw2,
    const float* __restrict__ den1, const float* __restrict__ den2,
    const float* __restrict__ self1, const float* __restrict__ self2,
    const float* __restrict__ m1, const float* __restrict__ m2,
    const unsigned short* __restrict__ xb,
    unsigned short* __restrict__ xa1b, unsigned short* __restrict__ xa2b, int N){
  int tid = threadIdx.x;
  int g = tid >> 4, hl = tid & 15;
  int grpbase = tid & 48;
  int d = blockIdx.y * 16 + g;
  if (d >= N) return;
  int colbase = blockIdx.x * 128 + hl * 8;
  float inv1 = 1.f / den1[d], inv2 = 1.f / den2[d];
  int deg = counts[d], off = offs[d];
  float acc1[8] = {0,0,0,0,0,0,0,0}, acc2[8] = {0,0,0,0,0,0,0,0};
  const unsigned short* Xb = xb + colbase;
  for (int base = 0; base < deg; base += 16){
    int i = base + hl;
    int s = 0; float w1 = 0.f, w2 = 0.f;
    if (i < deg){
      int p = off + i;
      s = nsrc[p];
      w1 = nw1[p] * inv1;
      w2 = nw2[p] * inv2;
    }
    int cnt = min(16, deg - base);
#pragma unroll 4
    for (int j = 0; j < cnt; j++){
      int sj = __shfl(s, grpbase + j);
      float w1j = __shfl(w1, grpbase + j);
      float w2j = __shfl(w2, grpbase + j);
      int4 u = *(const int4*)(Xb + (size_t)sj * IN_C);
      AGG_FMA8(acc1, w1j, u)
      AGG_FMA8(acc2, w2j, u)
    }
  }
  {
    float ws1 = expf(self1[d] - m1[d]) * inv1;
    float ws2 = expf(self2[d] - m2[d]) * inv2;
    int4 u = *(const int4*)(Xb + (size_t)d * IN_C);
    AGG_FMA8(acc1, ws1, u)
    AGG_FMA8(acc2, ws2, u)
  }
  size_t outb = (size_t)d * IN_C + colbase;
  i32x4 o1, o2;
  o1.x = (int)((unsigned)f2b(acc1[0]) | ((unsigned)f2b(acc1[1]) << 16));
  o1.y = (int)((unsigned)f2b(acc1[2]) | ((unsigned)f2b(acc1[3]) << 16));
  o1.z = (int)((unsigned)f2b(acc1[4]) | ((unsigned)f2b(acc1[5]) << 16));
  o1.w = (int)((unsigned)f2b(acc1[6]) | ((unsigned)f2b(acc1[7]) << 16));
  o2.x = (int)((unsigned)f2b(acc2[0]) | ((unsigned)f2b(acc2[1]) << 16));
  o2.y = (int)((unsigned)f2b(acc2[2]) | ((unsigned)f2b(acc2[3]) << 16));
  o2.z = (int)((unsigned)f2b(acc2[4]) | ((unsigned)f2b(acc2[5]) << 16));
  o2.w = (int)((unsigned)f2b(acc2[6]) | ((unsigned)f2b(acc2[7]) << 16));
  __builtin_nontemporal_store(o1, (i32x4*)(xa1b + outb));
  __builtin_nontemporal_store(o2, (i32x4*)(xa2b + outb));
}

// ---------------- fused GEMM-H: 64x128 tiles, R0 simple loop (best measured) +
// T2 swizzle (conflicts=0, R2-verified) + NT stores + __launch_bounds__(256,4):
// R0 ran at Occupancy 26% (~2 blocks/CU) while latency-bound -> raise TLP to 4
// blocks/CU so other blocks' MFMA covers each block's barrier drain.

__global__ __launch_bounds__(256, 4) void gemmh_kernel(const unsigned short* __restrict__ A1,
                                                       const unsigned short* __restrict__ A2,
                                                       const unsigned short* __restrict__ BT,
                                                       const float* __restrict__ b1,
                                                       const float* __restrict__ b2,
                                                       const float* __restrict__ prelu_a,
                                                       unsigned short* __restrict__ hsum,
                                                       unsigned short* __restrict__ hdiff,
                                                       int M, int Mtiles, int perx){
  const int bid = blockIdx.x;
  const int xcd = bid & 7;
  const int li = bid >> 3;
  const int bn_t = li & 7;
  const int bm_t = xcd * perx + (li >> 3);
  if (bm_t >= Mtiles) return;
  const int bm = bm_t * 64, bn = bn_t * 128;
  __shared__ unsigned short Al[64 * 32];   // 4 KB
  __shared__ unsigned short Bl[128 * 32];  // 8 KB
  const int t = threadIdx.x;
  const int lane = t & 63, wid = t >> 6;
  const int wj = wid;                      // wave -> 32-col quarter
  const int l16 = lane & 15, q = lane >> 4;
  const int qs = (q ^ ((l16 >> 1) & 3)) * 8;               // swizzled read slot
  const int lch = (((lane & 3) ^ ((lane >> 3) & 3)) * 8);  // pre-swizzled source chunk
  f32x4 acc1[4][2] = {};
  f32x4 acc2[4][2] = {};
  const int arow = bm + wid * 16 + (lane >> 2);
  const int brow0 = bn + wid * 32 + (lane >> 2);
  const int ga = min(arow, M - 1);
  const unsigned short* pa1 = A1 + (size_t)ga * IN_C + lch;
  const unsigned short* pa2 = A2 + (size_t)ga * IN_C + lch;
  const unsigned short* pb0 = BT + (size_t)brow0 * IN_C + lch;
  const unsigned short* pb1 = BT + (size_t)(brow0 + 16) * IN_C + lch;
  const size_t boff2 = (size_t)OUT_C * IN_C;
  // ---- GEMM 1 ----
  for (int k0 = 0; k0 < IN_C; k0 += 32){
    GLOAD_LDS16(pa1 + k0, &Al[(wid * 16) * 32]);
    GLOAD_LDS16(pb0 + k0, &Bl[(wid * 32) * 32]);
    GLOAD_LDS16(pb1 + k0, &Bl[(wid * 32 + 16) * 32]);
    __syncthreads();
    frag8 af[4], bf[2];
#pragma unroll
    for (int mi = 0; mi < 4; mi++) af[mi] = *(const frag8*)&Al[(mi*16 + l16) * 32 + qs];
#pragma unroll
    for (int nj = 0; nj < 2; nj++) bf[nj] = *(const frag8*)&Bl[(wj*32 + nj*16 + l16) * 32 + qs];
#pragma unroll
    for (int mi = 0; mi < 4; mi++)
#pragma unroll
      for (int nj = 0; nj < 2; nj++)
        acc1[mi][nj] = __builtin_amdgcn_mfma_f32_16x16x32_bf16(af[mi], bf[nj], acc1[mi][nj], 0, 0, 0);
    __syncthreads();
  }
  // ---- GEMM 2 ----
  for (int k0 = 0; k0 < IN_C; k0 += 32){
    GLOAD_LDS16(pa2 + k0, &Al[(wid * 16) * 32]);
    GLOAD_LDS16(pb0 + boff2 + k0, &Bl[(wid * 32) * 32]);
    GLOAD_LDS16(pb1 + boff2 + k0, &Bl[(wid * 32 + 16) * 32]);
    __syncthreads();
    frag8 af[4], bf[2];
#pragma unroll
    for (int mi = 0; mi < 4; mi++) af[mi] = *(const frag8*)&Al[(mi*16 + l16) * 32 + qs];
#pragma unroll
    for (int nj = 0; nj < 2; nj++) bf[nj] = *(const frag8*)&Bl[(wj*32 + nj*16 + l16) * 32 + qs];
#pragma unroll
    for (int mi = 0; mi < 4; mi++)
#pragma unroll
      for (int nj = 0; nj < 2; nj++)
        acc2[mi][nj] = __builtin_amdgcn_mfma_f32_16x16x32_bf16(af[mi], bf[nj], acc2[mi][nj], 0, 0, 0);
    __syncthreads();
  }
  float pa = prelu_a[0];
#pragma unroll
  for (int mi = 0; mi < 4; mi++){
#pragma unroll
    for (int r = 0; r < 4; r++){
      int row = bm + mi*16 + q*4 + r;
      if (row >= M) continue;
#pragma unroll
      for (int nj = 0; nj < 2; nj++){
        int col = bn + wj*32 + nj*16 + l16;
        float v1 = acc1[mi][nj][r] + b1[col];
        v1 = v1 >= 0.f ? v1 : pa * v1;
        float v2 = acc2[mi][nj][r] + b2[col];
        v2 = v2 >= 0.f ? v2 : pa * v2;
        size_t idx = (size_t)row * OUT_C + col;
        __builtin_nontemporal_store(f2b(v1 + v2), &hsum[idx]);
        __builtin_nontemporal_store(f2b(v1 - v2), &hdiff[idx]);
      }
    }
  }
}

// ---------------- GEMM2: 64x128 tiles; colsum += sum_rows tanh(hsum @ Wp1 + bp1) ---------

__global__ __launch_bounds__(256, 4) void gemm2_kernel(const unsigned short* __restrict__ A,
                                                       const unsigned short* __restrict__ BT,
                                                       const float* __restrict__ bp1,
                                                       float* __restrict__ colsum,
                                                       int M, int Mtiles, int perx){
  const int bid = blockIdx.x;
  const int xcd = bid & 7;
  const int li = bid >> 3;
  const int bn_t = li & 7;
  const int bm_t = xcd * perx + (li >> 3);
  if (bm_t >= Mtiles) return;
  const int bm = bm_t * 64, bn = bn_t * 128;
  __shared__ unsigned short Al[64 * 32];
  __shared__ unsigned short Bl[128 * 32];
  __shared__ float cs[128];
  const int t = threadIdx.x;
  const int lane = t & 63, wid = t >> 6;
  const int wj = wid;
  const int l16 = lane & 15, q = lane >> 4;
  const int qs = (q ^ ((l16 >> 1) & 3)) * 8;
  const int lch = (((lane & 3) ^ ((lane >> 3) & 3)) * 8);
  if (t < 128) cs[t] = 0.f;
  f32x4 acc[4][2] = {};
  const int arow = bm + wid * 16 + (lane >> 2);
  const int brow0 = bn + wid * 32 + (lane >> 2);
  const int ga = min(arow, M - 1);
  const unsigned short* pa = A + (size_t)ga * OUT_C + lch;
  const unsigned short* pb0 = BT + (size_t)brow0 * OUT_C + lch;
  const unsigned short* pb1 = BT + (size_t)(brow0 + 16) * OUT_C + lch;
  for (int k0 = 0; k0 < OUT_C; k0 += 32){
    GLOAD_LDS16(pa + k0, &Al[(wid * 16) * 32]);
    GLOAD_LDS16(pb0 + k0, &Bl[(wid * 32) * 32]);
    GLOAD_LDS16(pb1 + k0, &Bl[(wid * 32 + 16) * 32]);
    __syncthreads();
    frag8 af[4], bf[2];
#pragma unroll
    for (int mi = 0; mi < 4; mi++) af[mi] = *(const frag8*)&Al[(mi*16 + l16) * 32 + qs];
#pragma unroll
    for (int nj = 0; nj < 2; nj++) bf[nj] = *(const frag8*)&Bl[(wj*32 + nj*16 + l16) * 32 + qs];
#pragma unroll
    for (int mi = 0; mi < 4; mi++)
#pragma unroll
      for (int nj = 0; nj < 2; nj++)
        acc[mi][nj] = __builtin_amdgcn_mfma_f32_16x16x32_bf16(af[mi], bf[nj], acc[mi][nj], 0, 0, 0);
    __syncthreads();
  }
#pragma unroll
  for (int nj = 0; nj < 2; nj++){
    int col = bn + wj*32 + nj*16 + l16;
    float bias = bp1[col];
    float p = 0.f;
#pragma unroll
    for (int mi = 0; mi < 4; mi++){
#pragma unroll
      for (int r = 0; r < 4; r++){
        int row = bm + mi*16 + q*4 + r;
        float tv = tanhf(acc[mi][nj][r] + bias);
        if (row < M) p += tv;
      }
    }
    p += __shfl_xor(p, 16);
    p += __shfl_xor(p, 32);
    if (q == 0) atomicAdd(&cs[wj*32 + nj*16 + l16], p);
  }
  __syncthreads();
  if (t < 128) atomicAdd(&colsum[bn + t], cs[t]);
}

// ---------------- semantic attention tail ----------------

__global__ void wproj_kernel(const float* __restrict__ colsum, const float* __restrict__ Wp2,
                             float* __restrict__ wv){
  int o = blockIdx.x * 256 + threadIdx.x;
  int c0 = blockIdx.y * 128;
  float acc = 0.f;
  for (int c = c0; c < c0 + 128; c++) acc += colsum[c] * Wp2[(size_t)c * OUT_C + o];
  atomicAdd(&wv[o], acc);
}

__global__ __launch_bounds__(1024) void softmax_kernel(const float* __restrict__ wv,
                                                       float* __restrict__ att, float invN){
  int o = threadIdx.x;
  __shared__ float red[1024];
  float w = wv[o] * invN;
  red[o] = w; __syncthreads();
  for (int s = 512; s > 0; s >>= 1){ if (o < s) red[o] = fmaxf(red[o], red[o + s]); __syncthreads(); }
  float m = red[0]; __syncthreads();
  float e = expf(w - m);
  red[o] = e; __syncthreads();
  for (int s = 512; s > 0; s >>= 1){ if (o < s) red[o] += red[o + s]; __syncthreads(); }
  att[o] = e / red[0];
}

__global__ void combine_kernel(const float* __restrict__ att, const unsigned short* __restrict__ hs,
                               const unsigned short* __restrict__ hd, float* __restrict__ out, int total8){
  int i = blockIdx.x * 256 + threadIdx.x;
  if (i >= total8) return;
  int colb = (i & 127) * 8;
  int4 us = ((const int4*)hs)[i];
  int4 ud = ((const int4*)hd)[i];
  float4 a0 = *(const float4*)(att + colb);
  float4 a1 = *(const float4*)(att + colb + 4);
  float o[8]; float sv, dv;
  sv = __uint_as_float(((unsigned)us.x) << 16);        dv = __uint_as_float(((unsigned)ud.x) << 16);
  o[0] = 0.5f * sv + (a0.x - 0.5f) * dv;
  sv = __uint_as_float(((unsigned)us.x) & 0xffff0000u); dv = __uint_as_float(((unsigned)ud.x) & 0xffff0000u);
  o[1] = 0.5f * sv + (a0.y - 0.5f) * dv;
  sv = __uint_as_float(((unsigned)us.y) << 16);        dv = __uint_as_float(((unsigned)ud.y) << 16);
  o[2] = 0.5f * sv + (a0.z - 0.5f) * dv;
  sv = __uint_as_float(((unsigned)us.y) & 0xffff0000u); dv = __uint_as_float(((unsigned)ud.y) & 0xffff0000u);
  o[3] = 0.5f * sv + (a0.w - 0.5f) * dv;
  sv = __uint_as_float(((unsigned)us.z) << 16);        dv = __uint_as_float(((unsigned)ud.z) << 16);
  o[4] = 0.5f * sv + (a1.x - 0.5f) * dv;
  sv = __uint_as_float(((unsigned)us.z) & 0xffff0000u); dv = __uint_as_float(((unsigned)ud.z) & 0xffff0000u);
  o[5] = 0.5f * sv + (a1.y - 0.5f) * dv;
  sv = __uint_as_float(((unsigned)us.w) << 16);        dv = __uint_as_float(((unsigned)ud.w) << 16);
  o[6] = 0.5f * sv + (a1.z - 0.5f) * dv;
  sv = __uint_as_float(((unsigned)us.w) & 0xffff0000u); dv = __uint_as_float(((unsigned)ud.w) & 0xffff0000u);
  o[7] = 0.5f * sv + (a1.w - 0.5f) * dv;
  f32x4 f0; f0[0] = o[0]; f0[1] = o[1]; f0[2] = o[2]; f0[3] = o[3];
  f32x4 f1; f1[0] = o[4]; f1[1] = o[5]; f1[2] = o[6]; f1[3] = o[7];
  __builtin_nontemporal_store(f0, (f32x4*)(out + (size_t)i * 8));
  __builtin_nontemporal_store(f1, (f32x4*)(out + (size_t)i * 8 + 4));
}

// ---------------- launch ----------------

extern "C" void kernel_launch(void* const* d_in, const int* in_sizes, int n_in,
                              void* d_out, int out_size, void* d_ws, size_t ws_size,
                              hipStream_t stream){
  const float* x      = (const float*)d_in[0];
  const int*   edge   = (const int*)d_in[1];
  const float* W1     = (const float*)d_in[2];
  const float* a_src1 = (const float*)d_in[3];
  const float* a_dst1 = (const float*)d_in[4];
  const float* b1     = (const float*)d_in[5];
  const float* W2     = (const float*)d_in[6];
  const float* a_src2 = (const float*)d_in[7];
  const float* a_dst2 = (const float*)d_in[8];
  const float* b2     = (const float*)d_in[9];
  const float* prelu_a= (const float*)d_in[10];
  const float* Wp1    = (const float*)d_in[11];
  const float* bp1    = (const float*)d_in[12];
  const float* Wp2    = (const float*)d_in[13];
  const int N = in_sizes[0] / IN_C;
  const int E = in_sizes[1] / 2;
  const int* srcArr = edge;
  const int* dstArr = edge + E;

  char* ws = (char*)d_ws;
  size_t o = 0;
  auto alloc = [&](size_t b) -> char* {
    char* p = ws + o;
    o = (o + b + 255) & ~(size_t)255;
    return p;
  };
  unsigned short* xb    = (unsigned short*)alloc((size_t)N * IN_C * 2);
  unsigned short* WT    = (unsigned short*)alloc((size_t)NC2 * IN_C * 2);
  unsigned short* Wp1T  = (unsigned short*)alloc((size_t)OUT_C * OUT_C * 2);
  unsigned short* xa1b  = (unsigned short*)alloc((size_t)N * IN_C * 2);
  unsigned short* xa2b  = (unsigned short*)alloc((size_t)N * IN_C * 2);
  unsigned short* hsum  = (unsigned short*)alloc((size_t)N * OUT_C * 2);
  unsigned short* hdiff = (unsigned short*)alloc((size_t)N * OUT_C * 2);
  float*          uv    = (float*)alloc(4 * IN_C * 4);
  float*          as1   = (float*)alloc((size_t)4 * N * 4);
  float* ad1 = as1 + N; float* as2 = as1 + 2 * N; float* ad2 = as1 + 3 * N;
  float*          self1 = (float*)alloc((size_t)2 * N * 4); float* self2 = self1 + N;
  unsigned*       m1e   = (unsigned*)alloc((size_t)2 * N * 4); unsigned* m2e = m1e + N;
  float*          m1    = (float*)alloc((size_t)2 * N * 4); float* m2 = m1 + N;
  float*          den1  = (float*)alloc((size_t)2 * N * 4); float* den2 = den1 + N;
  int*            counts= (int*)alloc((size_t)N * 4);
  int*            offs  = (int*)alloc((size_t)(N + 1) * 4);
  int*            cursor= (int*)alloc((size_t)N * 4);
  int*            bsum  = (int*)alloc(64 * 4);
  int*            nsrc  = (int*)alloc((size_t)E * 4);
  float*          nw1   = (float*)alloc((size_t)E * 4);
  float*          nw2   = (float*)alloc((size_t)E * 4);
  float*          colsum= (float*)alloc(OUT_C * 4);
  float*          wv    = (float*)alloc(OUT_C * 4);
  float*          att   = (float*)alloc(OUT_C * 4);

  const int Mtiles = (N + 63) / 64;
  const int perx = (Mtiles + 7) / 8;
  const int gemmgrid = 8 * perx * 8;
  const int nchunk = (N + 255) / 256;

  prep_kernel<<<2560, 256, 0, stream>>>(W1, W2, Wp1, a_src1, a_dst1, a_src2, a_dst2, WT, Wp1T, uv);
  alpha_kernel<<<N, 256, 0, stream>>>(x, uv, xb, as1, ad1, as2, ad2, self1, self2, m1e, m2e,
                                      counts, cursor, colsum, wv);
  histmax_kernel<<<(E + 255) / 256, 256, 0, stream>>>(srcArr, dstArr, as1, ad1, as2, ad2,
                                                      counts, m1e, m2e, E);
  scanA_kernel<<<nchunk, 256, 0, stream>>>(counts, offs, bsum, N);
  scanB_kernel<<<1, 64, 0, stream>>>(bsum, nchunk);
  scanC_kernel<<<nchunk, 256, 0, stream>>>(offs, bsum, m1e, m2e, self1, self2, m1, m2,
                                           den1, den2, N);
  scatterexp_kernel<<<(E + 255) / 256, 256, 0, stream>>>(srcArr, dstArr, offs, cursor,
                                                         as1, ad1, as2, ad2, m1, m2,
                                                         nsrc, nw1, nw2, den1, den2, E);
  aggx_kernel<<<dim3(4, (N + 15) / 16), 256, 0, stream>>>(counts, offs, nsrc, nw1, nw2, den1, den2,
                                                          self1, self2, m1, m2, xb, xa1b, xa2b, N);
  gemmh_kernel<<<gemmgrid, 256, 0, stream>>>(xa1b, xa2b, WT, b1, b2, prelu_a,
                                             hsum, hdiff, N, Mtiles, perx);
  gemm2_kernel<<<gemmgrid, 256, 0, stream>>>(hsum, Wp1T, bp1, colsum, N, Mtiles, perx);
  wproj_kernel<<<dim3(4, 8), 256, 0, stream>>>(colsum, Wp2, wv);
  softmax_kernel<<<1, 1024, 0, stream>>>(wv, att, 1.0f / (float)N);
  combine_kernel<<<(N * OUT_C / 8 + 255) / 256, 256, 0, stream>>>(att, hsum, hdiff, (float*)d_out,
                                                                  N * OUT_C / 8);
}

// Round 6
// 295.257 us; speedup vs baseline: 1.3129x; 1.1301x over previous
//
#include <hip/hip_runtime.h>

#define IN_C 512
#define OUT_C 1024
#define NC2 2048
#define NEG_SLOPE 0.2f

typedef short frag8 __attribute__((ext_vector_type(8)));
typedef float f32x4 __attribute__((ext_vector_type(4)));

#define GLOAD_LDS16(g, l) __builtin_amdgcn_global_load_lds(\
    (const __attribute__((address_space(1))) void*)(g), \
    (__attribute__((address_space(3))) void*)(l), 16, 0, 0)

__device__ __forceinline__ unsigned short f2b(float f){
  unsigned u = __float_as_uint(f);
  unsigned r = (u + 0x7fffu + ((u >> 16) & 1u)) >> 16;
  return (unsigned short)r;
}
__device__ __forceinline__ float leaky(float v){ return v >= 0.f ? v : NEG_SLOPE * v; }

// ---------------- fused preprocessing ----------------

__global__ void prep_kernel(const float* __restrict__ W1, const float* __restrict__ W2,
                            const float* __restrict__ Wp1,
                            const float* __restrict__ a_src1, const float* __restrict__ a_dst1,
                            const float* __restrict__ a_src2, const float* __restrict__ a_dst2,
                            unsigned short* __restrict__ WT, unsigned short* __restrict__ Wp1T,
                            float* __restrict__ uv){
  __shared__ float tile[32][33];
  int b = blockIdx.x;
  int tx = threadIdx.x & 31, ty = threadIdx.x >> 5;
  if (b < 1024){
    const float* in = (b >> 9) ? W2 : W1;
    int rowOff = (b >> 9) * OUT_C;
    int bb = b & 511;
    int c0 = (bb & 31) * 32, r0 = (bb >> 5) * 32;
    for (int i = ty; i < 32; i += 8)
      tile[i][tx] = in[(size_t)(r0 + i) * OUT_C + c0 + tx];
    __syncthreads();
    for (int i = ty; i < 32; i += 8)
      WT[(size_t)(c0 + i + rowOff) * IN_C + r0 + tx] = f2b(tile[tx][i]);
  } else if (b < 2048){
    int bb = b - 1024;
    int c0 = (bb & 31) * 32, r0 = (bb >> 5) * 32;
    for (int i = ty; i < 32; i += 8)
      tile[i][tx] = Wp1[(size_t)(r0 + i) * OUT_C + c0 + tx];
    __syncthreads();
    for (int i = ty; i < 32; i += 8)
      Wp1T[(size_t)(c0 + i) * OUT_C + r0 + tx] = f2b(tile[tx][i]);
  } else {
    int g = (b - 2048) * 4 + (threadIdx.x >> 6);
    int lane = threadIdx.x & 63;
    int which = g >> 9;
    int i = g & 511;
    const float* W = (which < 2) ? W1 : W2;
    const float* a = (which == 0) ? a_src1 : (which == 1) ? a_dst1 : (which == 2) ? a_src2 : a_dst2;
    const float* row = W + (size_t)i * OUT_C;
    float s = 0.f;
    for (int j = lane; j < OUT_C; j += 64) s += row[j] * a[j];
    for (int off = 32; off; off >>= 1) s += __shfl_down(s, off);
    if (lane == 0) uv[which * IN_C + i] = s;
  }
}

// ---------------- alpha + self-e + x->bf16 + zero-init (float4 loads, G13) --------

__global__ void alpha_kernel(const float* __restrict__ x, const float* __restrict__ uv,
                             unsigned short* __restrict__ xb,
                             float* __restrict__ as1, float* __restrict__ ad1,
                             float* __restrict__ as2, float* __restrict__ ad2,
                             float* __restrict__ self1, float* __restrict__ self2,
                             int* counts, int* cursor, float* colsum, float* wv){
  int n = blockIdx.x;
  int w = threadIdx.x >> 6, lane = threadIdx.x & 63;
  __shared__ float sh[4];
  if (threadIdx.x == 0){ counts[n] = 0; cursor[n] = 0; }
  if (n < 8){
    int i = n * 256 + threadIdx.x;
    if (i < 1024) colsum[i] = 0.f; else wv[i - 1024] = 0.f;
  }
  const float4* rv = (const float4*)(x + (size_t)n * IN_C);
  const float4* un = (const float4*)(uv + w * IN_C);
  float4 v0 = rv[lane], v1 = rv[lane + 64];
  float4 u0 = un[lane], u1 = un[lane + 64];
  float s = v0.x*u0.x + v0.y*u0.y + v0.z*u0.z + v0.w*u0.w
          + v1.x*u1.x + v1.y*u1.y + v1.z*u1.z + v1.w*u1.w;
  if (w == 0){
    ushort4 p0, p1;
    p0.x = f2b(v0.x); p0.y = f2b(v0.y); p0.z = f2b(v0.z); p0.w = f2b(v0.w);
    p1.x = f2b(v1.x); p1.y = f2b(v1.y); p1.z = f2b(v1.z); p1.w = f2b(v1.w);
    *(ushort4*)(xb + (size_t)n * IN_C + lane * 4) = p0;
    *(ushort4*)(xb + (size_t)n * IN_C + 256 + lane * 4) = p1;
  }
  for (int off = 32; off; off >>= 1) s += __shfl_down(s, off);
  if (lane == 0){
    sh[w] = s;
    if (w == 0) as1[n] = s;
    else if (w == 1) ad1[n] = s;
    else if (w == 2) as2[n] = s;
    else ad2[n] = s;
  }
  __syncthreads();
  if (threadIdx.x == 0){
    self1[n] = leaky(sh[0] + sh[1]);   // exp() applied later; no segment-max needed:
    self2[n] = leaky(sh[2] + sh[3]);   // |e| <~ 7 so exp(e) is safe in f32 and the
  }                                    // softmax ratio is identical without max-shift
}

// ---------------- CSR build + edge softmax (max-free) ----------------

__global__ void histcount_kernel(const int* __restrict__ dst, int* counts, int E){
  int e = blockIdx.x * 256 + threadIdx.x;
  if (e < E) atomicAdd(&counts[dst[e]], 1);
}

__global__ void scanA_kernel(const int* __restrict__ counts, int* __restrict__ offs,
                             int* __restrict__ bsum, int n){
  __shared__ int wsum[4];
  int i = blockIdx.x * 256 + threadIdx.x;
  int wave = threadIdx.x >> 6, lane = threadIdx.x & 63;
  int v = (i < n) ? counts[i] : 0;
  int sc = v;
  for (int o = 1; o < 64; o <<= 1){
    int t = __shfl_up(sc, o);
    if (lane >= o) sc += t;
  }
  if (lane == 63) wsum[wave] = sc;
  __syncthreads();
  int wp = 0, tot = 0;
#pragma unroll
  for (int k = 0; k < 4; k++){
    int ws = wsum[k];
    if (k < wave) wp += ws;
    tot += ws;
  }
  if (i < n) offs[i] = wp + sc - v;
  if (threadIdx.x == 0) bsum[blockIdx.x] = tot;
}

__global__ void scanB_kernel(int* __restrict__ bsum, int nb){
  int lane = threadIdx.x;
  int v = (lane < nb) ? bsum[lane] : 0;
  int sc = v;
  for (int o = 1; o < 64; o <<= 1){
    int t = __shfl_up(sc, o);
    if (lane >= o) sc += t;
  }
  if (lane < nb) bsum[lane] = sc - v;
}

// scanC + denom-init fused: den starts at exp(self)
__global__ void scanC_kernel(int* __restrict__ offs, const int* __restrict__ bsum,
                             const float* __restrict__ self1, const float* __restrict__ self2,
                             float* __restrict__ den1, float* __restrict__ den2, int n){
  int i = blockIdx.x * 256 + threadIdx.x;
  if (i >= n) return;
  offs[i] += bsum[blockIdx.x];
  den1[i] = expf(self1[i]);
  den2[i] = expf(self2[i]);
}

__global__ void scatterexp_kernel(const int* __restrict__ src, const int* __restrict__ dst,
                                  const int* __restrict__ offs, int* cursor,
                                  const float* __restrict__ as1, const float* __restrict__ ad1,
                                  const float* __restrict__ as2, const float* __restrict__ ad2,
                                  int* __restrict__ nsrc, float* __restrict__ nw1, float* __restrict__ nw2,
                                  float* den1, float* den2, int E){
  int e = blockIdx.x * 256 + threadIdx.x;
  if (e >= E) return;
  int s = src[e], d = dst[e];
  int p = atomicAdd(&cursor[d], 1);
  int idx = offs[d] + p;
  float x1 = expf(leaky(as1[s] + ad1[d]));
  float x2 = expf(leaky(as2[s] + ad2[d]));
  nsrc[idx] = s; nw1[idx] = x1; nw2[idx] = x2;
  atomicAdd(&den1[d], x1);
  atomicAdd(&den2[d], x2);
}

// ---------------- aggregate-first: wave-per-dst, full 512-col row per edge --------
// One 64-lane wave owns one dst; per edge one 1024B fully-coalesced row read
// (was 4 separate 256B visits across 4 blocks) + one shfl-broadcast triple.

#define AGG_FMA8(ACC, W, U) \
  ACC[0] += (W) * __uint_as_float(((unsigned)(U).x) << 16); \
  ACC[1] += (W) * __uint_as_float(((unsigned)(U).x) & 0xffff0000u); \
  ACC[2] += (W) * __uint_as_float(((unsigned)(U).y) << 16); \
  ACC[3] += (W) * __uint_as_float(((unsigned)(U).y) & 0xffff0000u); \
  ACC[4] += (W) * __uint_as_float(((unsigned)(U).z) << 16); \
  ACC[5] += (W) * __uint_as_float(((unsigned)(U).z) & 0xffff0000u); \
  ACC[6] += (W) * __uint_as_float(((unsigned)(U).w) << 16); \
  ACC[7] += (W) * __uint_as_float(((unsigned)(U).w) & 0xffff0000u);

__global__ __launch_bounds__(256) void aggx_kernel(
    const int* __restrict__ counts, const int* __restrict__ offs,
    const int* __restrict__ nsrc, const float* __restrict__ nw1, const float* __restrict__ nw2,
    const float* __restrict__ den1, const float* __restrict__ den2,
    const float* __restrict__ self1, const float* __restrict__ self2,
    const unsigned short* __restrict__ xb,
    unsigned short* __restrict__ xa1b, unsigned short* __restrict__ xa2b, int N){
  int wid = threadIdx.x >> 6, lane = threadIdx.x & 63;
  int d = blockIdx.x * 4 + wid;
  if (d >= N) return;
  float inv1 = 1.f / den1[d], inv2 = 1.f / den2[d];
  int deg = counts[d], off = offs[d];
  float acc1[8] = {0,0,0,0,0,0,0,0}, acc2[8] = {0,0,0,0,0,0,0,0};
  const unsigned short* Xb = xb + lane * 8;
  for (int base = 0; base < deg; base += 64){
    int i = base + lane;
    int s = 0; float w1 = 0.f, w2 = 0.f;
    if (i < deg){
      int p = off + i;
      s = nsrc[p];
      w1 = nw1[p] * inv1;
      w2 = nw2[p] * inv2;
    }
    int cnt = min(64, deg - base);
#pragma unroll 4
    for (int j = 0; j < cnt; j++){
      int sj = __shfl(s, j);
      float w1j = __shfl(w1, j);
      float w2j = __shfl(w2, j);
      int4 u = *(const int4*)(Xb + (size_t)sj * IN_C);
      AGG_FMA8(acc1, w1j, u)
      AGG_FMA8(acc2, w2j, u)
    }
  }
  {
    float ws1 = expf(self1[d]) * inv1;
    float ws2 = expf(self2[d]) * inv2;
    int4 u = *(const int4*)(Xb + (size_t)d * IN_C);
    AGG_FMA8(acc1, ws1, u)
    AGG_FMA8(acc2, ws2, u)
  }
  size_t outb = (size_t)d * IN_C + lane * 8;
  int4 o1, o2;
  o1.x = (int)((unsigned)f2b(acc1[0]) | ((unsigned)f2b(acc1[1]) << 16));
  o1.y = (int)((unsigned)f2b(acc1[2]) | ((unsigned)f2b(acc1[3]) << 16));
  o1.z = (int)((unsigned)f2b(acc1[4]) | ((unsigned)f2b(acc1[5]) << 16));
  o1.w = (int)((unsigned)f2b(acc1[6]) | ((unsigned)f2b(acc1[7]) << 16));
  o2.x = (int)((unsigned)f2b(acc2[0]) | ((unsigned)f2b(acc2[1]) << 16));
  o2.y = (int)((unsigned)f2b(acc2[2]) | ((unsigned)f2b(acc2[3]) << 16));
  o2.z = (int)((unsigned)f2b(acc2[4]) | ((unsigned)f2b(acc2[5]) << 16));
  o2.w = (int)((unsigned)f2b(acc2[6]) | ((unsigned)f2b(acc2[7]) << 16));
  *(int4*)(xa1b + outb) = o1;
  *(int4*)(xa2b + outb) = o2;
}

// ---------------- fused GEMM-H: exact R0 structure (best measured: 49.6 us) -------

__global__ __launch_bounds__(256) void gemmh_kernel(const unsigned short* __restrict__ A1,
                                                    const unsigned short* __restrict__ A2,
                                                    const unsigned short* __restrict__ BT,
                                                    const float* __restrict__ b1,
                                                    const float* __restrict__ b2,
                                                    const float* __restrict__ prelu_a,
                                                    unsigned short* __restrict__ hsum,
                                                    unsigned short* __restrict__ hdiff,
                                                    int M, int Mtiles, int perx){
  const int bid = blockIdx.x;
  const int xcd = bid & 7;
  const int li = bid >> 3;
  const int bn_t = li & 7;
  const int bm_t = xcd * perx + (li >> 3);
  if (bm_t >= Mtiles) return;
  const int bm = bm_t * 64, bn = bn_t * 128;
  __shared__ unsigned short Al[64 * 32];   // 4 KB
  __shared__ unsigned short Bl[128 * 32];  // 8 KB
  const int t = threadIdx.x;
  const int lane = t & 63, wid = t >> 6;
  const int wj = wid;
  const int l16 = lane & 15, q = lane >> 4;
  const int lch = (lane & 3) * 8;
  f32x4 acc1[4][2] = {};
  f32x4 acc2[4][2] = {};
  const int arow = bm + wid * 16 + (lane >> 2);
  const int brow0 = bn + wid * 32 + (lane >> 2);
  const int ga = min(arow, M - 1);
  const unsigned short* pa1 = A1 + (size_t)ga * IN_C + lch;
  const unsigned short* pa2 = A2 + (size_t)ga * IN_C + lch;
  const unsigned short* pb0 = BT + (size_t)brow0 * IN_C + lch;
  const unsigned short* pb1 = BT + (size_t)(brow0 + 16) * IN_C + lch;
  const size_t boff2 = (size_t)OUT_C * IN_C;
  // ---- GEMM 1 ----
  for (int k0 = 0; k0 < IN_C; k0 += 32){
    GLOAD_LDS16(pa1 + k0, &Al[(wid * 16) * 32]);
    GLOAD_LDS16(pb0 + k0, &Bl[(wid * 32) * 32]);
    GLOAD_LDS16(pb1 + k0, &Bl[(wid * 32 + 16) * 32]);
    __syncthreads();
    frag8 af[4], bf[2];
#pragma unroll
    for (int mi = 0; mi < 4; mi++) af[mi] = *(const frag8*)&Al[(mi*16 + l16) * 32 + q*8];
#pragma unroll
    for (int nj = 0; nj < 2; nj++) bf[nj] = *(const frag8*)&Bl[(wj*32 + nj*16 + l16) * 32 + q*8];
#pragma unroll
    for (int mi = 0; mi < 4; mi++)
#pragma unroll
      for (int nj = 0; nj < 2; nj++)
        acc1[mi][nj] = __builtin_amdgcn_mfma_f32_16x16x32_bf16(af[mi], bf[nj], acc1[mi][nj], 0, 0, 0);
    __syncthreads();
  }
  // ---- GEMM 2 ----
  for (int k0 = 0; k0 < IN_C; k0 += 32){
    GLOAD_LDS16(pa2 + k0, &Al[(wid * 16) * 32]);
    GLOAD_LDS16(pb0 + boff2 + k0, &Bl[(wid * 32) * 32]);
    GLOAD_LDS16(pb1 + boff2 + k0, &Bl[(wid * 32 + 16) * 32]);
    __syncthreads();
    frag8 af[4], bf[2];
#pragma unroll
    for (int mi = 0; mi < 4; mi++) af[mi] = *(const frag8*)&Al[(mi*16 + l16) * 32 + q*8];
#pragma unroll
    for (int nj = 0; nj < 2; nj++) bf[nj] = *(const frag8*)&Bl[(wj*32 + nj*16 + l16) * 32 + q*8];
#pragma unroll
    for (int mi = 0; mi < 4; mi++)
#pragma unroll
      for (int nj = 0; nj < 2; nj++)
        acc2[mi][nj] = __builtin_amdgcn_mfma_f32_16x16x32_bf16(af[mi], bf[nj], acc2[mi][nj], 0, 0, 0);
    __syncthreads();
  }
  float pa = prelu_a[0];
#pragma unroll
  for (int mi = 0; mi < 4; mi++){
#pragma unroll
    for (int r = 0; r < 4; r++){
      int row = bm + mi*16 + q*4 + r;
      if (row >= M) continue;
#pragma unroll
      for (int nj = 0; nj < 2; nj++){
        int col = bn + wj*32 + nj*16 + l16;
        float v1 = acc1[mi][nj][r] + b1[col];
        v1 = v1 >= 0.f ? v1 : pa * v1;
        float v2 = acc2[mi][nj][r] + b2[col];
        v2 = v2 >= 0.f ? v2 : pa * v2;
        size_t idx = (size_t)row * OUT_C + col;
        hsum[idx]  = f2b(v1 + v2);
        hdiff[idx] = f2b(v1 - v2);
      }
    }
  }
}

// ---------------- GEMM2: exact R0 structure ----------------

__global__ __launch_bounds__(256) void gemm2_kernel(const unsigned short* __restrict__ A,
                                                    const unsigned short* __restrict__ BT,
                                                    const float* __restrict__ bp1,
                                                    float* __restrict__ colsum,
                                                    int M, int Mtiles, int perx){
  const int bid = blockIdx.x;
  const int xcd = bid & 7;
  const int li = bid >> 3;
  const int bn_t = li & 7;
  const int bm_t = xcd * perx + (li >> 3);
  if (bm_t >= Mtiles) return;
  const int bm = bm_t * 64, bn = bn_t * 128;
  __shared__ unsigned short Al[64 * 32];
  __shared__ unsigned short Bl[128 * 32];
  __shared__ float cs[128];
  const int t = threadIdx.x;
  const int lane = t & 63, wid = t >> 6;
  const int wj = wid;
  const int l16 = lane & 15, q = lane >> 4;
  const int lch = (lane & 3) * 8;
  if (t < 128) cs[t] = 0.f;
  f32x4 acc[4][2] = {};
  const int arow = bm + wid * 16 + (lane >> 2);
  const int brow0 = bn + wid * 32 + (lane >> 2);
  const int ga = min(arow, M - 1);
  const unsigned short* pa = A + (size_t)ga * OUT_C + lch;
  const unsigned short* pb0 = BT + (size_t)brow0 * OUT_C + lch;
  const unsigned short* pb1 = BT + (size_t)(brow0 + 16) * OUT_C + lch;
  for (int k0 = 0; k0 < OUT_C; k0 += 32){
    GLOAD_LDS16(pa + k0, &Al[(wid * 16) * 32]);
    GLOAD_LDS16(pb0 + k0, &Bl[(wid * 32) * 32]);
    GLOAD_LDS16(pb1 + k0, &Bl[(wid * 32 + 16) * 32]);
    __syncthreads();
    frag8 af[4], bf[2];
#pragma unroll
    for (int mi = 0; mi < 4; mi++) af[mi] = *(const frag8*)&Al[(mi*16 + l16) * 32 + q*8];
#pragma unroll
    for (int nj = 0; nj < 2; nj++) bf[nj] = *(const frag8*)&Bl[(wj*32 + nj*16 + l16) * 32 + q*8];
#pragma unroll
    for (int mi = 0; mi < 4; mi++)
#pragma unroll
      for (int nj = 0; nj < 2; nj++)
        acc[mi][nj] = __builtin_amdgcn_mfma_f32_16x16x32_bf16(af[mi], bf[nj], acc[mi][nj], 0, 0, 0);
    __syncthreads();
  }
#pragma unroll
  for (int nj = 0; nj < 2; nj++){
    int col = bn + wj*32 + nj*16 + l16;
    float bias = bp1[col];
    float p = 0.f;
#pragma unroll
    for (int mi = 0; mi < 4; mi++){
#pragma unroll
      for (int r = 0; r < 4; r++){
        int row = bm + mi*16 + q*4 + r;
        float tv = tanhf(acc[mi][nj][r] + bias);
        if (row < M) p += tv;
      }
    }
    p += __shfl_xor(p, 16);
    p += __shfl_xor(p, 32);
    if (q == 0) atomicAdd(&cs[wj*32 + nj*16 + l16], p);
  }
  __syncthreads();
  if (t < 128) atomicAdd(&colsum[bn + t], cs[t]);
}

// ---------------- semantic attention tail ----------------

__global__ void wproj_kernel(const float* __restrict__ colsum, const float* __restrict__ Wp2,
                             float* __restrict__ wv){
  int o = blockIdx.x * 256 + threadIdx.x;
  int c0 = blockIdx.y * 128;
  float acc = 0.f;
  for (int c = c0; c < c0 + 128; c++) acc += colsum[c] * Wp2[(size_t)c * OUT_C + o];
  atomicAdd(&wv[o], acc);
}

__global__ __launch_bounds__(1024) void softmax_kernel(const float* __restrict__ wv,
                                                       float* __restrict__ att, float invN){
  int o = threadIdx.x;
  __shared__ float red[1024];
  float w = wv[o] * invN;
  red[o] = w; __syncthreads();
  for (int s = 512; s > 0; s >>= 1){ if (o < s) red[o] = fmaxf(red[o], red[o + s]); __syncthreads(); }
  float m = red[0]; __syncthreads();
  float e = expf(w - m);
  red[o] = e; __syncthreads();
  for (int s = 512; s > 0; s >>= 1){ if (o < s) red[o] += red[o + s]; __syncthreads(); }
  att[o] = e / red[0];
}

__global__ void combine_kernel(const float* __restrict__ att, const unsigned short* __restrict__ hs,
                               const unsigned short* __restrict__ hd, float* __restrict__ out, int total8){
  int i = blockIdx.x * 256 + threadIdx.x;
  if (i >= total8) return;
  int colb = (i & 127) * 8;
  int4 us = ((const int4*)hs)[i];
  int4 ud = ((const int4*)hd)[i];
  float4 a0 = *(const float4*)(att + colb);
  float4 a1 = *(const float4*)(att + colb + 4);
  float o[8]; float sv, dv;
  sv = __uint_as_float(((unsigned)us.x) << 16);        dv = __uint_as_float(((unsigned)ud.x) << 16);
  o[0] = 0.5f * sv + (a0.x - 0.5f) * dv;
  sv = __uint_as_float(((unsigned)us.x) & 0xffff0000u); dv = __uint_as_float(((unsigned)ud.x) & 0xffff0000u);
  o[1] = 0.5f * sv + (a0.y - 0.5f) * dv;
  sv = __uint_as_float(((unsigned)us.y) << 16);        dv = __uint_as_float(((unsigned)ud.y) << 16);
  o[2] = 0.5f * sv + (a0.z - 0.5f) * dv;
  sv = __uint_as_float(((unsigned)us.y) & 0xffff0000u); dv = __uint_as_float(((unsigned)ud.y) & 0xffff0000u);
  o[3] = 0.5f * sv + (a0.w - 0.5f) * dv;
  sv = __uint_as_float(((unsigned)us.z) << 16);        dv = __uint_as_float(((unsigned)ud.z) << 16);
  o[4] = 0.5f * sv + (a1.x - 0.5f) * dv;
  sv = __uint_as_float(((unsigned)us.z) & 0xffff0000u); dv = __uint_as_float(((unsigned)ud.z) & 0xffff0000u);
  o[5] = 0.5f * sv + (a1.y - 0.5f) * dv;
  sv = __uint_as_float(((unsigned)us.w) << 16);        dv = __uint_as_float(((unsigned)ud.w) << 16);
  o[6] = 0.5f * sv + (a1.z - 0.5f) * dv;
  sv = __uint_as_float(((unsigned)us.w) & 0xffff0000u); dv = __uint_as_float(((unsigned)ud.w) & 0xffff0000u);
  o[7] = 0.5f * sv + (a1.w - 0.5f) * dv;
  float4 f0; f0.x = o[0]; f0.y = o[1]; f0.z = o[2]; f0.w = o[3];
  float4 f1; f1.x = o[4]; f1.y = o[5]; f1.z = o[6]; f1.w = o[7];
  *(float4*)(out + (size_t)i * 8) = f0;
  *(float4*)(out + (size_t)i * 8 + 4) = f1;
}

// ---------------- launch ----------------

extern "C" void kernel_launch(void* const* d_in, const int* in_sizes, int n_in,
                              void* d_out, int out_size, void* d_ws, size_t ws_size,
                              hipStream_t stream){
  const float* x      = (const float*)d_in[0];
  const int*   edge   = (const int*)d_in[1];
  const float* W1     = (const float*)d_in[2];
  const float* a_src1 = (const float*)d_in[3];
  const float* a_dst1 = (const float*)d_in[4];
  const float* b1     = (const float*)d_in[5];
  const float* W2     = (const float*)d_in[6];
  const float* a_src2 = (const float*)d_in[7];
  const float* a_dst2 = (const float*)d_in[8];
  const float* b2     = (const float*)d_in[9];
  const float* prelu_a= (const float*)d_in[10];
  const float* Wp1    = (const float*)d_in[11];
  const float* bp1    = (const float*)d_in[12];
  const float* Wp2    = (const float*)d_in[13];
  const int N = in_sizes[0] / IN_C;
  const int E = in_sizes[1] / 2;
  const int* srcArr = edge;
  const int* dstArr = edge + E;

  char* ws = (char*)d_ws;
  size_t o = 0;
  auto alloc = [&](size_t b) -> char* {
    char* p = ws + o;
    o = (o + b + 255) & ~(size_t)255;
    return p;
  };
  unsigned short* xb    = (unsigned short*)alloc((size_t)N * IN_C * 2);
  unsigned short* WT    = (unsigned short*)alloc((size_t)NC2 * IN_C * 2);
  unsigned short* Wp1T  = (unsigned short*)alloc((size_t)OUT_C * OUT_C * 2);
  unsigned short* xa1b  = (unsigned short*)alloc((size_t)N * IN_C * 2);
  unsigned short* xa2b  = (unsigned short*)alloc((size_t)N * IN_C * 2);
  unsigned short* hsum  = (unsigned short*)alloc((size_t)N * OUT_C * 2);
  unsigned short* hdiff = (unsigned short*)alloc((size_t)N * OUT_C * 2);
  float*          uv    = (float*)alloc(4 * IN_C * 4);
  float*          as1   = (float*)alloc((size_t)4 * N * 4);
  float* ad1 = as1 + N; float* as2 = as1 + 2 * N; float* ad2 = as1 + 3 * N;
  float*          self1 = (float*)alloc((size_t)2 * N * 4); float* self2 = self1 + N;
  float*          den1  = (float*)alloc((size_t)2 * N * 4); float* den2 = den1 + N;
  int*            counts= (int*)alloc((size_t)N * 4);
  int*            offs  = (int*)alloc((size_t)(N + 1) * 4);
  int*            cursor= (int*)alloc((size_t)N * 4);
  int*            bsum  = (int*)alloc(64 * 4);
  int*            nsrc  = (int*)alloc((size_t)E * 4);
  float*          nw1   = (float*)alloc((size_t)E * 4);
  float*          nw2   = (float*)alloc((size_t)E * 4);
  float*          colsum= (float*)alloc(OUT_C * 4);
  float*          wv    = (float*)alloc(OUT_C * 4);
  float*          att   = (float*)alloc(OUT_C * 4);

  const int Mtiles = (N + 63) / 64;
  const int perx = (Mtiles + 7) / 8;
  const int gemmgrid = 8 * perx * 8;
  const int nchunk = (N + 255) / 256;

  prep_kernel<<<2560, 256, 0, stream>>>(W1, W2, Wp1, a_src1, a_dst1, a_src2, a_dst2, WT, Wp1T, uv);
  alpha_kernel<<<N, 256, 0, stream>>>(x, uv, xb, as1, ad1, as2, ad2, self1, self2,
                                      counts, cursor, colsum, wv);
  histcount_kernel<<<(E + 255) / 256, 256, 0, stream>>>(dstArr, counts, E);
  scanA_kernel<<<nchunk, 256, 0, stream>>>(counts, offs, bsum, N);
  scanB_kernel<<<1, 64, 0, stream>>>(bsum, nchunk);
  scanC_kernel<<<nchunk, 256, 0, stream>>>(offs, bsum, self1, self2, den1, den2, N);
  scatterexp_kernel<<<(E + 255) / 256, 256, 0, stream>>>(srcArr, dstArr, offs, cursor,
                                                         as1, ad1, as2, ad2,
                                                         nsrc, nw1, nw2, den1, den2, E);
  aggx_kernel<<<(N + 3) / 4, 256, 0, stream>>>(counts, offs, nsrc, nw1, nw2, den1, den2,
                                               self1, self2, xb, xa1b, xa2b, N);
  gemmh_kernel<<<gemmgrid, 256, 0, stream>>>(xa1b, xa2b, WT, b1, b2, prelu_a,
                                             hsum, hdiff, N, Mtiles, perx);
  gemm2_kernel<<<gemmgrid, 256, 0, stream>>>(hsum, Wp1T, bp1, colsum, N, Mtiles, perx);
  wproj_kernel<<<dim3(4, 8), 256, 0, stream>>>(colsum, Wp2, wv);
  softmax_kernel<<<1, 1024, 0, stream>>>(wv, att, 1.0f / (float)N);
  combine_kernel<<<(N * OUT_C / 8 + 255) / 256, 256, 0, stream>>>(att, hsum, hdiff, (float*)d_out,
                                                                  N * OUT_C / 8);
}

// Round 7
// 279.896 us; speedup vs baseline: 1.3850x; 1.0549x over previous
//
#include <hip/hip_runtime.h>

#define IN_C 512
#define OUT_C 1024
#define NC2 2048
#define NEG_SLOPE 0.2f

typedef short frag8 __attribute__((ext_vector_type(8)));
typedef float f32x4 __attribute__((ext_vector_type(4)));

#define GLOAD_LDS16(g, l) __builtin_amdgcn_global_load_lds(\
    (const __attribute__((address_space(1))) void*)(g), \
    (__attribute__((address_space(3))) void*)(l), 16, 0, 0)

__device__ __forceinline__ unsigned short f2b(float f){
  unsigned u = __float_as_uint(f);
  unsigned r = (u + 0x7fffu + ((u >> 16) & 1u)) >> 16;
  return (unsigned short)r;
}
__device__ __forceinline__ float leaky(float v){ return v >= 0.f ? v : NEG_SLOPE * v; }

// ---------------- fused preprocessing (+ counts/cursor zeroing) ----------------

__global__ void prep_kernel(const float* __restrict__ W1, const float* __restrict__ W2,
                            const float* __restrict__ Wp1,
                            const float* __restrict__ a_src1, const float* __restrict__ a_dst1,
                            const float* __restrict__ a_src2, const float* __restrict__ a_dst2,
                            unsigned short* __restrict__ WT, unsigned short* __restrict__ Wp1T,
                            float* __restrict__ uv, int* __restrict__ counts,
                            int* __restrict__ cursor, int N){
  __shared__ float tile[32][33];
  int b = blockIdx.x;
  int tx = threadIdx.x & 31, ty = threadIdx.x >> 5;
  if (b < 1024){
    const float* in = (b >> 9) ? W2 : W1;
    int rowOff = (b >> 9) * OUT_C;
    int bb = b & 511;
    int c0 = (bb & 31) * 32, r0 = (bb >> 5) * 32;
    for (int i = ty; i < 32; i += 8)
      tile[i][tx] = in[(size_t)(r0 + i) * OUT_C + c0 + tx];
    __syncthreads();
    for (int i = ty; i < 32; i += 8)
      WT[(size_t)(c0 + i + rowOff) * IN_C + r0 + tx] = f2b(tile[tx][i]);
  } else if (b < 2048){
    int bb = b - 1024;
    int c0 = (bb & 31) * 32, r0 = (bb >> 5) * 32;
    for (int i = ty; i < 32; i += 8)
      tile[i][tx] = Wp1[(size_t)(r0 + i) * OUT_C + c0 + tx];
    __syncthreads();
    for (int i = ty; i < 32; i += 8)
      Wp1T[(size_t)(c0 + i) * OUT_C + r0 + tx] = f2b(tile[tx][i]);
  } else if (b < 2560){
    int g = (b - 2048) * 4 + (threadIdx.x >> 6);
    int lane = threadIdx.x & 63;
    int which = g >> 9;
    int i = g & 511;
    const float* W = (which < 2) ? W1 : W2;
    const float* a = (which == 0) ? a_src1 : (which == 1) ? a_dst1 : (which == 2) ? a_src2 : a_dst2;
    const float* row = W + (size_t)i * OUT_C;
    float s = 0.f;
    for (int j = lane; j < OUT_C; j += 64) s += row[j] * a[j];
    for (int off = 32; off; off >>= 1) s += __shfl_down(s, off);
    if (lane == 0) uv[which * IN_C + i] = s;
  } else {
    int i = (b - 2560) * 256 + threadIdx.x;
    if (i < N){ counts[i] = 0; cursor[i] = 0; }
  }
}

// ---------------- alpha (packed outputs) + fused edge histogram ----------------

__global__ void alphahist_kernel(const float* __restrict__ x, const float* __restrict__ uv,
                                 const int* __restrict__ dst,
                                 unsigned short* __restrict__ xb,
                                 float2* __restrict__ sa, float2* __restrict__ da,
                                 float2* __restrict__ ese,
                                 int* __restrict__ counts,
                                 float* __restrict__ colsum, float* __restrict__ wv,
                                 int N, int E){
  int b = blockIdx.x;
  if (b >= N){
    int e = (b - N) * 256 + threadIdx.x;
    if (e < E) atomicAdd(&counts[dst[e]], 1);
    return;
  }
  int n = b;
  int w = threadIdx.x >> 6, lane = threadIdx.x & 63;
  __shared__ float sh[4];
  if (n < 8){
    int i = n * 256 + threadIdx.x;
    if (i < 1024) colsum[i] = 0.f; else wv[i - 1024] = 0.f;
  }
  const float4* rv = (const float4*)(x + (size_t)n * IN_C);
  const float4* un = (const float4*)(uv + w * IN_C);
  float4 v0 = rv[lane], v1 = rv[lane + 64];
  float4 u0 = un[lane], u1 = un[lane + 64];
  float s = v0.x*u0.x + v0.y*u0.y + v0.z*u0.z + v0.w*u0.w
          + v1.x*u1.x + v1.y*u1.y + v1.z*u1.z + v1.w*u1.w;
  if (w == 0){
    ushort4 p0, p1;
    p0.x = f2b(v0.x); p0.y = f2b(v0.y); p0.z = f2b(v0.z); p0.w = f2b(v0.w);
    p1.x = f2b(v1.x); p1.y = f2b(v1.y); p1.z = f2b(v1.z); p1.w = f2b(v1.w);
    *(ushort4*)(xb + (size_t)n * IN_C + lane * 4) = p0;
    *(ushort4*)(xb + (size_t)n * IN_C + 256 + lane * 4) = p1;
  }
  for (int off = 32; off; off >>= 1) s += __shfl_down(s, off);
  if (lane == 0) sh[w] = s;
  __syncthreads();
  if (threadIdx.x == 0){
    float2 vsa; vsa.x = sh[0]; vsa.y = sh[2];
    float2 vda; vda.x = sh[1]; vda.y = sh[3];
    sa[n] = vsa; da[n] = vda;
    float2 es;                               // max-free softmax validated R6:
    es.x = expf(leaky(sh[0] + sh[1]));       // |e| small enough that exp() is
    es.y = expf(leaky(sh[2] + sh[3]));       // f32-safe without max-shift
    ese[n] = es;
  }
}

// ---------------- single-block scan (replaces scanA/B/C) ----------------

__global__ __launch_bounds__(1024) void scan_kernel(const int* __restrict__ counts,
                                                    int* __restrict__ offs, int n){
  __shared__ int ws[16];
  __shared__ int base_s;
  int tid = threadIdx.x, lane = tid & 63, wave = tid >> 6;
  if (tid == 0) base_s = 0;
  __syncthreads();
  for (int base = 0; base < n; base += 1024){
    int i = base + tid;
    int v = (i < n) ? counts[i] : 0;
    int sc = v;
    for (int o = 1; o < 64; o <<= 1){
      int t = __shfl_up(sc, o);
      if (lane >= o) sc += t;
    }
    if (lane == 63) ws[wave] = sc;
    __syncthreads();
    int wp = 0, tot = 0;
#pragma unroll
    for (int k = 0; k < 16; k++){ int w_ = ws[k]; if (k < wave) wp += w_; tot += w_; }
    if (i < n) offs[i] = base_s + wp + sc - v;
    __syncthreads();
    if (tid == 0) base_s += tot;
    __syncthreads();
  }
}

// ---------------- CSR scatter (den atomics removed; den computed in aggx) --------

__global__ void csr_kernel(const int* __restrict__ src, const int* __restrict__ dst,
                           const int* __restrict__ offs, int* cursor,
                           int* __restrict__ nsrc, int E){
  int e = blockIdx.x * 256 + threadIdx.x;
  if (e >= E) return;
  int d = dst[e];
  int p = atomicAdd(&cursor[d], 1);
  nsrc[offs[d] + p] = src[e];
}

// ---------------- aggregate-first: wave-per-dst, on-the-fly exp + in-wave den ----
// Accumulates UNNORMALIZED sum(exp(e)*row) and den = sum(exp(e)); divides once at
// the end (linear). sa/da/ese are 80-160 KB -> L2-resident gathers.

#define AGG_FMA8(ACC, W, U) \
  ACC[0] += (W) * __uint_as_float(((unsigned)(U).x) << 16); \
  ACC[1] += (W) * __uint_as_float(((unsigned)(U).x) & 0xffff0000u); \
  ACC[2] += (W) * __uint_as_float(((unsigned)(U).y) << 16); \
  ACC[3] += (W) * __uint_as_float(((unsigned)(U).y) & 0xffff0000u); \
  ACC[4] += (W) * __uint_as_float(((unsigned)(U).z) << 16); \
  ACC[5] += (W) * __uint_as_float(((unsigned)(U).z) & 0xffff0000u); \
  ACC[6] += (W) * __uint_as_float(((unsigned)(U).w) << 16); \
  ACC[7] += (W) * __uint_as_float(((unsigned)(U).w) & 0xffff0000u);

__global__ __launch_bounds__(256) void aggx_kernel(
    const int* __restrict__ counts, const int* __restrict__ offs,
    const int* __restrict__ nsrc,
    const float2* __restrict__ sa, const float2* __restrict__ da,
    const float2* __restrict__ ese,
    const unsigned short* __restrict__ xb,
    unsigned short* __restrict__ xa1b, unsigned short* __restrict__ xa2b, int N){
  int wid = threadIdx.x >> 6, lane = threadIdx.x & 63;
  int d = blockIdx.x * 4 + wid;
  if (d >= N) return;
  float2 dad = da[d];
  int deg = counts[d], off = offs[d];
  float acc1[8] = {0,0,0,0,0,0,0,0}, acc2[8] = {0,0,0,0,0,0,0,0};
  float den1 = 0.f, den2 = 0.f;
  const unsigned short* Xb = xb + lane * 8;
  for (int base = 0; base < deg; base += 64){
    int i = base + lane;
    int s = 0; float x1 = 0.f, x2 = 0.f;
    if (i < deg){
      s = nsrc[off + i];
      float2 sas = sa[s];
      x1 = expf(leaky(sas.x + dad.x));
      x2 = expf(leaky(sas.y + dad.y));
    }
    den1 += x1; den2 += x2;
    int cnt = min(64, deg - base);
#pragma unroll 4
    for (int j = 0; j < cnt; j++){
      int sj = __shfl(s, j);
      float w1j = __shfl(x1, j);
      float w2j = __shfl(x2, j);
      int4 u = *(const int4*)(Xb + (size_t)sj * IN_C);
      AGG_FMA8(acc1, w1j, u)
      AGG_FMA8(acc2, w2j, u)
    }
  }
  for (int o = 32; o; o >>= 1){
    den1 += __shfl_xor(den1, o);
    den2 += __shfl_xor(den2, o);
  }
  float2 es = ese[d];
  {
    int4 u = *(const int4*)(Xb + (size_t)d * IN_C);
    AGG_FMA8(acc1, es.x, u)
    AGG_FMA8(acc2, es.y, u)
  }
  den1 += es.x; den2 += es.y;
  float inv1 = 1.f / den1, inv2 = 1.f / den2;
  size_t outb = (size_t)d * IN_C + lane * 8;
  int4 o1, o2;
  o1.x = (int)((unsigned)f2b(acc1[0]*inv1) | ((unsigned)f2b(acc1[1]*inv1) << 16));
  o1.y = (int)((unsigned)f2b(acc1[2]*inv1) | ((unsigned)f2b(acc1[3]*inv1) << 16));
  o1.z = (int)((unsigned)f2b(acc1[4]*inv1) | ((unsigned)f2b(acc1[5]*inv1) << 16));
  o1.w = (int)((unsigned)f2b(acc1[6]*inv1) | ((unsigned)f2b(acc1[7]*inv1) << 16));
  o2.x = (int)((unsigned)f2b(acc2[0]*inv2) | ((unsigned)f2b(acc2[1]*inv2) << 16));
  o2.y = (int)((unsigned)f2b(acc2[2]*inv2) | ((unsigned)f2b(acc2[3]*inv2) << 16));
  o2.z = (int)((unsigned)f2b(acc2[4]*inv2) | ((unsigned)f2b(acc2[5]*inv2) << 16));
  o2.w = (int)((unsigned)f2b(acc2[6]*inv2) | ((unsigned)f2b(acc2[7]*inv2) << 16));
  *(int4*)(xa1b + outb) = o1;
  *(int4*)(xa2b + outb) = o2;
}

// ---------------- fused GEMM-H: exact R0 structure (best measured: 49.6 us) -------

__global__ __launch_bounds__(256) void gemmh_kernel(const unsigned short* __restrict__ A1,
                                                    const unsigned short* __restrict__ A2,
                                                    const unsigned short* __restrict__ BT,
                                                    const float* __restrict__ b1,
                                                    const float* __restrict__ b2,
                                                    const float* __restrict__ prelu_a,
                                                    unsigned short* __restrict__ hsum,
                                                    unsigned short* __restrict__ hdiff,
                                                    int M, int Mtiles, int perx){
  const int bid = blockIdx.x;
  const int xcd = bid & 7;
  const int li = bid >> 3;
  const int bn_t = li & 7;
  const int bm_t = xcd * perx + (li >> 3);
  if (bm_t >= Mtiles) return;
  const int bm = bm_t * 64, bn = bn_t * 128;
  __shared__ unsigned short Al[64 * 32];   // 4 KB
  __shared__ unsigned short Bl[128 * 32];  // 8 KB
  const int t = threadIdx.x;
  const int lane = t & 63, wid = t >> 6;
  const int wj = wid;
  const int l16 = lane & 15, q = lane >> 4;
  const int lch = (lane & 3) * 8;
  f32x4 acc1[4][2] = {};
  f32x4 acc2[4][2] = {};
  const int arow = bm + wid * 16 + (lane >> 2);
  const int brow0 = bn + wid * 32 + (lane >> 2);
  const int ga = min(arow, M - 1);
  const unsigned short* pa1 = A1 + (size_t)ga * IN_C + lch;
  const unsigned short* pa2 = A2 + (size_t)ga * IN_C + lch;
  const unsigned short* pb0 = BT + (size_t)brow0 * IN_C + lch;
  const unsigned short* pb1 = BT + (size_t)(brow0 + 16) * IN_C + lch;
  const size_t boff2 = (size_t)OUT_C * IN_C;
  // ---- GEMM 1 ----
  for (int k0 = 0; k0 < IN_C; k0 += 32){
    GLOAD_LDS16(pa1 + k0, &Al[(wid * 16) * 32]);
    GLOAD_LDS16(pb0 + k0, &Bl[(wid * 32) * 32]);
    GLOAD_LDS16(pb1 + k0, &Bl[(wid * 32 + 16) * 32]);
    __syncthreads();
    frag8 af[4], bf[2];
#pragma unroll
    for (int mi = 0; mi < 4; mi++) af[mi] = *(const frag8*)&Al[(mi*16 + l16) * 32 + q*8];
#pragma unroll
    for (int nj = 0; nj < 2; nj++) bf[nj] = *(const frag8*)&Bl[(wj*32 + nj*16 + l16) * 32 + q*8];
#pragma unroll
    for (int mi = 0; mi < 4; mi++)
#pragma unroll
      for (int nj = 0; nj < 2; nj++)
        acc1[mi][nj] = __builtin_amdgcn_mfma_f32_16x16x32_bf16(af[mi], bf[nj], acc1[mi][nj], 0, 0, 0);
    __syncthreads();
  }
  // ---- GEMM 2 ----
  for (int k0 = 0; k0 < IN_C; k0 += 32){
    GLOAD_LDS16(pa2 + k0, &Al[(wid * 16) * 32]);
    GLOAD_LDS16(pb0 + boff2 + k0, &Bl[(wid * 32) * 32]);
    GLOAD_LDS16(pb1 + boff2 + k0, &Bl[(wid * 32 + 16) * 32]);
    __syncthreads();
    frag8 af[4], bf[2];
#pragma unroll
    for (int mi = 0; mi < 4; mi++) af[mi] = *(const frag8*)&Al[(mi*16 + l16) * 32 + q*8];
#pragma unroll
    for (int nj = 0; nj < 2; nj++) bf[nj] = *(const frag8*)&Bl[(wj*32 + nj*16 + l16) * 32 + q*8];
#pragma unroll
    for (int mi = 0; mi < 4; mi++)
#pragma unroll
      for (int nj = 0; nj < 2; nj++)
        acc2[mi][nj] = __builtin_amdgcn_mfma_f32_16x16x32_bf16(af[mi], bf[nj], acc2[mi][nj], 0, 0, 0);
    __syncthreads();
  }
  float pa = prelu_a[0];
#pragma unroll
  for (int mi = 0; mi < 4; mi++){
#pragma unroll
    for (int r = 0; r < 4; r++){
      int row = bm + mi*16 + q*4 + r;
      if (row >= M) continue;
#pragma unroll
      for (int nj = 0; nj < 2; nj++){
        int col = bn + wj*32 + nj*16 + l16;
        float v1 = acc1[mi][nj][r] + b1[col];
        v1 = v1 >= 0.f ? v1 : pa * v1;
        float v2 = acc2[mi][nj][r] + b2[col];
        v2 = v2 >= 0.f ? v2 : pa * v2;
        size_t idx = (size_t)row * OUT_C + col;
        hsum[idx]  = f2b(v1 + v2);
        hdiff[idx] = f2b(v1 - v2);
      }
    }
  }
}

// ---------------- GEMM2: exact R0 structure ----------------

__global__ __launch_bounds__(256) void gemm2_kernel(const unsigned short* __restrict__ A,
                                                    const unsigned short* __restrict__ BT,
                                                    const float* __restrict__ bp1,
                                                    float* __restrict__ colsum,
                                                    int M, int Mtiles, int perx){
  const int bid = blockIdx.x;
  const int xcd = bid & 7;
  const int li = bid >> 3;
  const int bn_t = li & 7;
  const int bm_t = xcd * perx + (li >> 3);
  if (bm_t >= Mtiles) return;
  const int bm = bm_t * 64, bn = bn_t * 128;
  __shared__ unsigned short Al[64 * 32];
  __shared__ unsigned short Bl[128 * 32];
  __shared__ float cs[128];
  const int t = threadIdx.x;
  const int lane = t & 63, wid = t >> 6;
  const int wj = wid;
  const int l16 = lane & 15, q = lane >> 4;
  const int lch = (lane & 3) * 8;
  if (t < 128) cs[t] = 0.f;
  f32x4 acc[4][2] = {};
  const int arow = bm + wid * 16 + (lane >> 2);
  const int brow0 = bn + wid * 32 + (lane >> 2);
  const int ga = min(arow, M - 1);
  const unsigned short* pa = A + (size_t)ga * OUT_C + lch;
  const unsigned short* pb0 = BT + (size_t)brow0 * OUT_C + lch;
  const unsigned short* pb1 = BT + (size_t)(brow0 + 16) * OUT_C + lch;
  for (int k0 = 0; k0 < OUT_C; k0 += 32){
    GLOAD_LDS16(pa + k0, &Al[(wid * 16) * 32]);
    GLOAD_LDS16(pb0 + k0, &Bl[(wid * 32) * 32]);
    GLOAD_LDS16(pb1 + k0, &Bl[(wid * 32 + 16) * 32]);
    __syncthreads();
    frag8 af[4], bf[2];
#pragma unroll
    for (int mi = 0; mi < 4; mi++) af[mi] = *(const frag8*)&Al[(mi*16 + l16) * 32 + q*8];
#pragma unroll
    for (int nj = 0; nj < 2; nj++) bf[nj] = *(const frag8*)&Bl[(wj*32 + nj*16 + l16) * 32 + q*8];
#pragma unroll
    for (int mi = 0; mi < 4; mi++)
#pragma unroll
      for (int nj = 0; nj < 2; nj++)
        acc[mi][nj] = __builtin_amdgcn_mfma_f32_16x16x32_bf16(af[mi], bf[nj], acc[mi][nj], 0, 0, 0);
    __syncthreads();
  }
#pragma unroll
  for (int nj = 0; nj < 2; nj++){
    int col = bn + wj*32 + nj*16 + l16;
    float bias = bp1[col];
    float p = 0.f;
#pragma unroll
    for (int mi = 0; mi < 4; mi++){
#pragma unroll
      for (int r = 0; r < 4; r++){
        int row = bm + mi*16 + q*4 + r;
        float tv = tanhf(acc[mi][nj][r] + bias);
        if (row < M) p += tv;
      }
    }
    p += __shfl_xor(p, 16);
    p += __shfl_xor(p, 32);
    if (q == 0) atomicAdd(&cs[wj*32 + nj*16 + l16], p);
  }
  __syncthreads();
  if (t < 128) atomicAdd(&colsum[bn + t], cs[t]);
}

// ---------------- semantic attention tail ----------------

__global__ void wproj_kernel(const float* __restrict__ colsum, const float* __restrict__ Wp2,
                             float* __restrict__ wv){
  int o = blockIdx.x * 256 + threadIdx.x;
  int c0 = blockIdx.y * 128;
  float acc = 0.f;
  for (int c = c0; c < c0 + 128; c++) acc += colsum[c] * Wp2[(size_t)c * OUT_C + o];
  atomicAdd(&wv[o], acc);
}

__global__ __launch_bounds__(1024) void softmax_kernel(const float* __restrict__ wv,
                                                       float* __restrict__ att, float invN){
  int o = threadIdx.x;
  __shared__ float red[1024];
  float w = wv[o] * invN;
  red[o] = w; __syncthreads();
  for (int s = 512; s > 0; s >>= 1){ if (o < s) red[o] = fmaxf(red[o], red[o + s]); __syncthreads(); }
  float m = red[0]; __syncthreads();
  float e = expf(w - m);
  red[o] = e; __syncthreads();
  for (int s = 512; s > 0; s >>= 1){ if (o < s) red[o] += red[o + s]; __syncthreads(); }
  att[o] = e / red[0];
}

__global__ void combine_kernel(const float* __restrict__ att, const unsigned short* __restrict__ hs,
                               const unsigned short* __restrict__ hd, float* __restrict__ out, int total8){
  int i = blockIdx.x * 256 + threadIdx.x;
  if (i >= total8) return;
  int colb = (i & 127) * 8;
  int4 us = ((const int4*)hs)[i];
  int4 ud = ((const int4*)hd)[i];
  float4 a0 = *(const float4*)(att + colb);
  float4 a1 = *(const float4*)(att + colb + 4);
  float o[8]; float sv, dv;
  sv = __uint_as_float(((unsigned)us.x) << 16);        dv = __uint_as_float(((unsigned)ud.x) << 16);
  o[0] = 0.5f * sv + (a0.x - 0.5f) * dv;
  sv = __uint_as_float(((unsigned)us.x) & 0xffff0000u); dv = __uint_as_float(((unsigned)ud.x) & 0xffff0000u);
  o[1] = 0.5f * sv + (a0.y - 0.5f) * dv;
  sv = __uint_as_float(((unsigned)us.y) << 16);        dv = __uint_as_float(((unsigned)ud.y) << 16);
  o[2] = 0.5f * sv + (a0.z - 0.5f) * dv;
  sv = __uint_as_float(((unsigned)us.y) & 0xffff0000u); dv = __uint_as_float(((unsigned)ud.y) & 0xffff0000u);
  o[3] = 0.5f * sv + (a0.w - 0.5f) * dv;
  sv = __uint_as_float(((unsigned)us.z) << 16);        dv = __uint_as_float(((unsigned)ud.z) << 16);
  o[4] = 0.5f * sv + (a1.x - 0.5f) * dv;
  sv = __uint_as_float(((unsigned)us.z) & 0xffff0000u); dv = __uint_as_float(((unsigned)ud.z) & 0xffff0000u);
  o[5] = 0.5f * sv + (a1.y - 0.5f) * dv;
  sv = __uint_as_float(((unsigned)us.w) << 16);        dv = __uint_as_float(((unsigned)ud.w) << 16);
  o[6] = 0.5f * sv + (a1.z - 0.5f) * dv;
  sv = __uint_as_float(((unsigned)us.w) & 0xffff0000u); dv = __uint_as_float(((unsigned)ud.w) & 0xffff0000u);
  o[7] = 0.5f * sv + (a1.w - 0.5f) * dv;
  float4 f0; f0.x = o[0]; f0.y = o[1]; f0.z = o[2]; f0.w = o[3];
  float4 f1; f1.x = o[4]; f1.y = o[5]; f1.z = o[6]; f1.w = o[7];
  *(float4*)(out + (size_t)i * 8) = f0;
  *(float4*)(out + (size_t)i * 8 + 4) = f1;
}

// ---------------- launch ----------------

extern "C" void kernel_launch(void* const* d_in, const int* in_sizes, int n_in,
                              void* d_out, int out_size, void* d_ws, size_t ws_size,
                              hipStream_t stream){
  const float* x      = (const float*)d_in[0];
  const int*   edge   = (const int*)d_in[1];
  const float* W1     = (const float*)d_in[2];
  const float* a_src1 = (const float*)d_in[3];
  const float* a_dst1 = (const float*)d_in[4];
  const float* b1     = (const float*)d_in[5];
  const float* W2     = (const float*)d_in[6];
  const float* a_src2 = (const float*)d_in[7];
  const float* a_dst2 = (const float*)d_in[8];
  const float* b2     = (const float*)d_in[9];
  const float* prelu_a= (const float*)d_in[10];
  const float* Wp1    = (const float*)d_in[11];
  const float* bp1    = (const float*)d_in[12];
  const float* Wp2    = (const float*)d_in[13];
  const int N = in_sizes[0] / IN_C;
  const int E = in_sizes[1] / 2;
  const int* srcArr = edge;
  const int* dstArr = edge + E;

  char* ws = (char*)d_ws;
  size_t o = 0;
  auto alloc = [&](size_t b) -> char* {
    char* p = ws + o;
    o = (o + b + 255) & ~(size_t)255;
    return p;
  };
  unsigned short* xb    = (unsigned short*)alloc((size_t)N * IN_C * 2);
  unsigned short* WT    = (unsigned short*)alloc((size_t)NC2 * IN_C * 2);
  unsigned short* Wp1T  = (unsigned short*)alloc((size_t)OUT_C * OUT_C * 2);
  unsigned short* xa1b  = (unsigned short*)alloc((size_t)N * IN_C * 2);
  unsigned short* xa2b  = (unsigned short*)alloc((size_t)N * IN_C * 2);
  unsigned short* hsum  = (unsigned short*)alloc((size_t)N * OUT_C * 2);
  unsigned short* hdiff = (unsigned short*)alloc((size_t)N * OUT_C * 2);
  float*          uv    = (float*)alloc(4 * IN_C * 4);
  float2*         sa    = (float2*)alloc((size_t)N * 8);
  float2*         da    = (float2*)alloc((size_t)N * 8);
  float2*         ese   = (float2*)alloc((size_t)N * 8);
  int*            counts= (int*)alloc((size_t)N * 4);
  int*            offs  = (int*)alloc((size_t)(N + 1) * 4);
  int*            cursor= (int*)alloc((size_t)N * 4);
  int*            nsrc  = (int*)alloc((size_t)E * 4);
  float*          colsum= (float*)alloc(OUT_C * 4);
  float*          wv    = (float*)alloc(OUT_C * 4);
  float*          att   = (float*)alloc(OUT_C * 4);

  const int Mtiles = (N + 63) / 64;
  const int perx = (Mtiles + 7) / 8;
  const int gemmgrid = 8 * perx * 8;
  const int zblocks = (N + 255) / 256;
  const int eblocks = (E + 255) / 256;

  prep_kernel<<<2560 + zblocks, 256, 0, stream>>>(W1, W2, Wp1, a_src1, a_dst1, a_src2, a_dst2,
                                                  WT, Wp1T, uv, counts, cursor, N);
  alphahist_kernel<<<N + eblocks, 256, 0, stream>>>(x, uv, dstArr, xb, sa, da, ese,
                                                    counts, colsum, wv, N, E);
  scan_kernel<<<1, 1024, 0, stream>>>(counts, offs, N);
  csr_kernel<<<eblocks, 256, 0, stream>>>(srcArr, dstArr, offs, cursor, nsrc, E);
  aggx_kernel<<<(N + 3) / 4, 256, 0, stream>>>(counts, offs, nsrc, sa, da, ese,
                                               xb, xa1b, xa2b, N);
  gemmh_kernel<<<gemmgrid, 256, 0, stream>>>(xa1b, xa2b, WT, b1, b2, prelu_a,
                                             hsum, hdiff, N, Mtiles, perx);
  gemm2_kernel<<<gemmgrid, 256, 0, stream>>>(hsum, Wp1T, bp1, colsum, N, Mtiles, perx);
  wproj_kernel<<<dim3(4, 8), 256, 0, stream>>>(colsum, Wp2, wv);
  softmax_kernel<<<1, 1024, 0, stream>>>(wv, att, 1.0f / (float)N);
  combine_kernel<<<(N * OUT_C / 8 + 255) / 256, 256, 0, stream>>>(att, hsum, hdiff, (float*)d_out,
                                                                  N * OUT_C / 8);
}